// Round 1
// baseline (1422.536 us; speedup 1.0000x reference)
//
#include <hip/hip_runtime.h>
#include <cstdint>
#include <cstddef>

// ---------------------------------------------------------------------------
// RezeroGCN: h0 = x@W_in+b_in; 4x { hW = h@W_c; agg = D^-1/2 A D^-1/2 hW;
//            h = beta*h + alpha*tanh(agg+b) }; out = log_softmax(h@W_out+b_out)
// Strategy: CSR-bucket edges by dst once per call (atomics only in build),
// per-layer aggregation = per-node wave gather (no atomics), fp32 vector GEMM
// with full W staged in LDS.
// ---------------------------------------------------------------------------

constexpr int K = 128;  // IN_C == HID == 128

// ---------------- degree / CSR build ----------------

__global__ void count_kernel(const int* __restrict__ dst, int* __restrict__ cnt, int E) {
    int e = blockIdx.x * 256 + threadIdx.x;
    if (e < E) atomicAdd(&cnt[dst[e]], 1);
}

__global__ void scan_partial(const int* __restrict__ cnt, int* __restrict__ bsum, int n) {
    __shared__ int sdata[256];
    int i = blockIdx.x * 256 + threadIdx.x;
    sdata[threadIdx.x] = (i < n) ? cnt[i] : 0;
    __syncthreads();
    for (int o = 128; o > 0; o >>= 1) {
        if (threadIdx.x < o) sdata[threadIdx.x] += sdata[threadIdx.x + o];
        __syncthreads();
    }
    if (threadIdx.x == 0) bsum[blockIdx.x] = sdata[0];
}

// single block exclusive scan of bsum[nb], nb <= 512
__global__ void scan_bsum(int* __restrict__ bsum, int nb) {
    __shared__ int buf[512];
    int t = threadIdx.x;
    int v = (t < nb) ? bsum[t] : 0;
    buf[t] = v;
    __syncthreads();
    for (int o = 1; o < 512; o <<= 1) {
        int add = (t >= o) ? buf[t - o] : 0;
        __syncthreads();
        buf[t] += add;
        __syncthreads();
    }
    if (t < nb) bsum[t] = buf[t] - v;  // exclusive
}

__global__ void scan_final(const int* __restrict__ cnt, const int* __restrict__ bsum,
                           int* __restrict__ off, int n) {
    __shared__ int buf[256];
    int t = threadIdx.x;
    int i = blockIdx.x * 256 + t;
    int v = (i < n) ? cnt[i] : 0;
    buf[t] = v;
    __syncthreads();
    for (int o = 1; o < 256; o <<= 1) {
        int add = (t >= o) ? buf[t - o] : 0;
        __syncthreads();
        buf[t] += add;
        __syncthreads();
    }
    int incl = buf[t];
    int base = bsum[blockIdx.x];
    if (i < n) off[i] = base + incl - v;
    if (i == n - 1) off[n] = base + incl;  // == E
}

__global__ void dinv_cur_kernel(const int* __restrict__ cnt, const int* __restrict__ off,
                                float* __restrict__ dinv, int* __restrict__ cur, int n) {
    int i = blockIdx.x * 256 + threadIdx.x;
    if (i < n) {
        dinv[i] = rsqrtf((float)cnt[i] + 1.0f);  // +1 self-loop; always > 0
        cur[i] = off[i];
    }
}

__global__ void fill_kernel(const int* __restrict__ src, const int* __restrict__ dst,
                            int* __restrict__ cur, int* __restrict__ csr, int E) {
    int e = blockIdx.x * 256 + threadIdx.x;
    if (e < E) {
        int p = atomicAdd(&cur[dst[e]], 1);
        csr[p] = src[e];
    }
}

// ---------------- GEMM: out[M,NOUT] = A[M,128] @ W[128,NOUT] (+bias) ----------------
// 256 threads, 64 rows/block, 4 threads/row, each thread NOUT/4 outputs.
// W fully staged in LDS; n = 4*tpos + 16*j keeps the 4 distinct float4 LDS
// addresses per wave access in distinct banks (16 same-row lanes broadcast).

template <int NOUT, bool BIAS>
__global__ __launch_bounds__(256) void gemm_kernel(
    const float* __restrict__ A, const float* __restrict__ W,
    const float* __restrict__ bias, float* __restrict__ out, int M)
{
    __shared__ float w_lds[K * NOUT];
    const int tid = threadIdx.x;
    constexpr int WVEC = K * NOUT / 4;
    {
        const float4* W4 = (const float4*)W;
        float4* L4 = (float4*)w_lds;
#pragma unroll
        for (int i = 0; i < WVEC / 256; ++i)
            L4[tid + i * 256] = W4[tid + i * 256];
    }
    __syncthreads();

    const int tpos = tid & 3;
    const int r = blockIdx.x * 64 + (tid >> 2);
    if (r >= M) return;

    constexpr int J = NOUT / 16;
    float4 acc[J];
#pragma unroll
    for (int j = 0; j < J; ++j) acc[j] = make_float4(0.f, 0.f, 0.f, 0.f);

    const float* arow = A + (size_t)r * K;
    for (int k0 = 0; k0 < K; k0 += 4) {
        float4 xv = *(const float4*)(arow + k0);
#pragma unroll
        for (int kk = 0; kk < 4; ++kk) {
            float xs = (&xv.x)[kk];
            const float* wrow = w_lds + (k0 + kk) * NOUT + tpos * 4;
#pragma unroll
            for (int j = 0; j < J; ++j) {
                float4 w = *(const float4*)(wrow + j * 16);
                acc[j].x += xs * w.x;
                acc[j].y += xs * w.y;
                acc[j].z += xs * w.z;
                acc[j].w += xs * w.w;
            }
        }
    }

    float* orow = out + (size_t)r * NOUT + tpos * 4;
#pragma unroll
    for (int j = 0; j < J; ++j) {
        float4 v = acc[j];
        if (BIAS) {
            float4 b = *(const float4*)(bias + tpos * 4 + j * 16);
            v.x += b.x; v.y += b.y; v.z += b.z; v.w += b.w;
        }
        *(float4*)(orow + j * 16) = v;
    }
}

// ---------------- aggregation + bias + tanh + rezero (in place on A) ----------------
// one wave per node; lane handles float2 of the 128 features.
// A[d] = beta*A[d] + alpha*tanh( dinv[d]*( sum_e dinv[src]*B[src] + dinv[d]*B[d] ) + b )

__global__ __launch_bounds__(256) void agg_kernel(
    const float* __restrict__ B, float* __restrict__ A,
    const float* __restrict__ dinv, const int* __restrict__ off,
    const int* __restrict__ csr, const float* __restrict__ bconv,
    const float* __restrict__ alpha, const float* __restrict__ beta, int n)
{
    int gid = blockIdx.x * 256 + threadIdx.x;
    int d = gid >> 6;
    int lane = threadIdx.x & 63;
    if (d >= n) return;

    const int c0 = lane * 2;
    float dd = dinv[d];
    int s0 = off[d], s1 = off[d + 1];

    float ax = 0.f, ay = 0.f;
    for (int j = s0; j < s1; ++j) {
        int s = csr[j];
        float w = dinv[s];
        float2 v = *(const float2*)(B + (size_t)s * K + c0);
        ax += w * v.x;
        ay += w * v.y;
    }
    {   // self loop
        float2 v = *(const float2*)(B + (size_t)d * K + c0);
        ax += dd * v.x;
        ay += dd * v.y;
    }
    float al = alpha[0], be = beta[0];
    float2 bb = *(const float2*)(bconv + c0);
    float2 inp = *(const float2*)(A + (size_t)d * K + c0);
    float hx = tanhf(dd * ax + bb.x);
    float hy = tanhf(dd * ay + bb.y);
    float2 o;
    o.x = be * inp.x + al * hx;
    o.y = be * inp.y + al * hy;
    *(float2*)(A + (size_t)d * K + c0) = o;
}

// ---------------- log_softmax over 64 cols, in place, one wave per row ----------------

__global__ __launch_bounds__(256) void lsm_kernel(float* __restrict__ out, int n) {
    int gid = blockIdx.x * 256 + threadIdx.x;
    int row = gid >> 6;
    int lane = threadIdx.x & 63;
    if (row >= n) return;
    float* p = out + (size_t)row * 64 + lane;
    float v = *p;
    float m = v;
#pragma unroll
    for (int o = 32; o > 0; o >>= 1) m = fmaxf(m, __shfl_xor(m, o));
    float e = expf(v - m);
    float s = e;
#pragma unroll
    for (int o = 32; o > 0; o >>= 1) s += __shfl_xor(s, o);
    *p = v - m - logf(s);
}

// ---------------------------------------------------------------------------

extern "C" void kernel_launch(void* const* d_in, const int* in_sizes, int n_in,
                              void* d_out, int out_size, void* d_ws, size_t ws_size,
                              hipStream_t stream)
{
    const float* x      = (const float*)d_in[0];
    const int*   ei     = (const int*)d_in[1];
    const float* W_in   = (const float*)d_in[2];
    const float* b_in   = (const float*)d_in[3];
    const float* W_conv = (const float*)d_in[4];
    const float* b_conv = (const float*)d_in[5];
    const float* alpha  = (const float*)d_in[6];
    const float* beta   = (const float*)d_in[7];
    const float* W_out  = (const float*)d_in[8];
    const float* b_out  = (const float*)d_in[9];
    float* out = (float*)d_out;

    const int N = in_sizes[0] / K;   // 100000
    const int E = in_sizes[1] / 2;   // 1600000
    const int L = in_sizes[6];       // 4

    const int* src = ei;
    const int* dst = ei + E;

    // workspace carve (fp32/int32), ~110 MB total
    float* A    = (float*)d_ws;            // N*128
    float* B_   = A + (size_t)N * K;       // N*128
    float* dinv = B_ + (size_t)N * K;      // N
    int* cnt  = (int*)(dinv + N);          // N
    int* off  = cnt + N;                   // N+1
    int* cur  = off + N + 1;               // N
    int* csr  = cur + N;                   // E
    int* bsum = csr + E;                   // ceil(N/256)

    const int nb = (N + 255) / 256;

    hipMemsetAsync(cnt, 0, (size_t)N * sizeof(int), stream);
    count_kernel<<<(E + 255) / 256, 256, 0, stream>>>(dst, cnt, E);
    scan_partial<<<nb, 256, 0, stream>>>(cnt, bsum, N);
    scan_bsum<<<1, 512, 0, stream>>>(bsum, nb);
    scan_final<<<nb, 256, 0, stream>>>(cnt, bsum, off, N);
    dinv_cur_kernel<<<(N + 255) / 256, 256, 0, stream>>>(cnt, off, dinv, cur, N);
    fill_kernel<<<(E + 255) / 256, 256, 0, stream>>>(src, dst, cur, csr, E);

    const int gblocks = (N + 63) / 64;
    gemm_kernel<128, true><<<gblocks, 256, 0, stream>>>(x, W_in, b_in, A, N);
    for (int l = 0; l < L; ++l) {
        gemm_kernel<128, false><<<gblocks, 256, 0, stream>>>(
            A, W_conv + (size_t)l * K * K, nullptr, B_, N);
        agg_kernel<<<(N * 64 + 255) / 256, 256, 0, stream>>>(
            B_, A, dinv, off, csr, b_conv + (size_t)l * K, alpha + l, beta + l, N);
    }
    gemm_kernel<64, true><<<gblocks, 256, 0, stream>>>(A, W_out, b_out, out, N);
    lsm_kernel<<<(N + 3) / 4, 256, 0, stream>>>(out, N);
}

// Round 2
// 1112.435 us; speedup vs baseline: 1.2788x; 1.2788x over previous
//
#include <hip/hip_runtime.h>
#include <cstdint>
#include <cstddef>

// ---------------------------------------------------------------------------
// RezeroGCN round 2: bf16 MFMA GEMMs (fp32 accum) + bf16 message gather.
// fp32 residual path preserved. CSR build unchanged (atomics only in build).
// ---------------------------------------------------------------------------

constexpr int K = 128;  // IN_C == HID == 128

typedef __bf16 bf16x8 __attribute__((ext_vector_type(8)));
typedef float f32x4 __attribute__((ext_vector_type(4)));

// manual RNE float->bf16 (no dependence on hip_bf16 internals)
__device__ inline uint16_t f2bf(float f) {
    union { float f; uint32_t u; } c; c.f = f;
    uint32_t r = (c.u + 0x7fffu + ((c.u >> 16) & 1u)) >> 16;
    return (uint16_t)r;
}
__device__ inline float blo(uint32_t u) { union { uint32_t i; float f; } c; c.i = u << 16; return c.f; }
__device__ inline float bhi(uint32_t u) { union { uint32_t i; float f; } c; c.i = u & 0xffff0000u; return c.f; }

// ---------------- degree / CSR build ----------------

__global__ void count_kernel(const int* __restrict__ dst, int* __restrict__ cnt, int E) {
    int e = blockIdx.x * 256 + threadIdx.x;
    if (e < E) atomicAdd(&cnt[dst[e]], 1);
}

__global__ void scan_partial(const int* __restrict__ cnt, int* __restrict__ bsum, int n) {
    __shared__ int sdata[256];
    int i = blockIdx.x * 256 + threadIdx.x;
    sdata[threadIdx.x] = (i < n) ? cnt[i] : 0;
    __syncthreads();
    for (int o = 128; o > 0; o >>= 1) {
        if (threadIdx.x < o) sdata[threadIdx.x] += sdata[threadIdx.x + o];
        __syncthreads();
    }
    if (threadIdx.x == 0) bsum[blockIdx.x] = sdata[0];
}

__global__ void scan_bsum(int* __restrict__ bsum, int nb) {
    __shared__ int buf[512];
    int t = threadIdx.x;
    int v = (t < nb) ? bsum[t] : 0;
    buf[t] = v;
    __syncthreads();
    for (int o = 1; o < 512; o <<= 1) {
        int add = (t >= o) ? buf[t - o] : 0;
        __syncthreads();
        buf[t] += add;
        __syncthreads();
    }
    if (t < nb) bsum[t] = buf[t] - v;  // exclusive
}

__global__ void scan_final(const int* __restrict__ cnt, const int* __restrict__ bsum,
                           int* __restrict__ off, int n) {
    __shared__ int buf[256];
    int t = threadIdx.x;
    int i = blockIdx.x * 256 + t;
    int v = (i < n) ? cnt[i] : 0;
    buf[t] = v;
    __syncthreads();
    for (int o = 1; o < 256; o <<= 1) {
        int add = (t >= o) ? buf[t - o] : 0;
        __syncthreads();
        buf[t] += add;
        __syncthreads();
    }
    int incl = buf[t];
    int base = bsum[blockIdx.x];
    if (i < n) off[i] = base + incl - v;
    if (i == n - 1) off[n] = base + incl;
}

__global__ void dinv_cur_kernel(const int* __restrict__ cnt, const int* __restrict__ off,
                                float* __restrict__ dinv, int* __restrict__ cur, int n) {
    int i = blockIdx.x * 256 + threadIdx.x;
    if (i < n) {
        dinv[i] = rsqrtf((float)cnt[i] + 1.0f);
        cur[i] = off[i];
    }
}

__global__ void fill_kernel(const int* __restrict__ src, const int* __restrict__ dst,
                            int* __restrict__ cur, int* __restrict__ csr, int E) {
    int e = blockIdx.x * 256 + threadIdx.x;
    if (e < E) {
        int p = atomicAdd(&cur[dst[e]], 1);
        csr[p] = src[e];
    }
}

// ---------------- weight transpose+convert: Wt[c][k] = bf16(W[k][c]) ----------------

__global__ void wconv_kernel(const float* __restrict__ W, uint16_t* __restrict__ Wt, int cols) {
    int idx = blockIdx.x * 256 + threadIdx.x;
    if (idx >= cols * K) return;
    int c = idx >> 7;          // output row (col of W)
    int k = idx & (K - 1);     // 0..127
    Wt[idx] = f2bf(W[(size_t)k * cols + c]);
}

// ---------------- MFMA GEMM: out[M,NOUT] = A[M,128] @ W[128,NOUT] (+bias) ----------
// 256 thr = 4 waves; wave computes 32 rows x NOUT. 16x16x32 bf16 MFMA, fp32 acc.
// A frag: lane l -> row (l&15), k = k0 + (l>>4)*8 + i
// B frag: lane l -> col (l&15), k = k0 + (l>>4)*8 + i   (from Wt[col][k], contiguous)
// D frag: lane l, reg i -> row (l>>4)*4 + i, col (l&15)

template <int NOUT, bool BIAS, bool A_FP32, bool OUT_F32, bool OUT_BF16>
__global__ __launch_bounds__(256) void mfma_gemm(
    const void* __restrict__ Aptr, const uint16_t* __restrict__ Wt,
    const float* __restrict__ bias, float* __restrict__ outF,
    uint16_t* __restrict__ outB, int M)
{
    constexpr int NT = NOUT / 16;
    const int tid = threadIdx.x;
    const int w = tid >> 6;
    const int l = tid & 63;
    const int lg = l >> 4;   // k-group
    const int lr = l & 15;   // row-in-tile (A) / col-in-tile (B,D)
    const int rbase = blockIdx.x * 128 + w * 32;
    const int r0c = min(rbase + lr, M - 1);
    const int r1c = min(rbase + 16 + lr, M - 1);

    f32x4 acc[2][NT] = {};

    for (int k0 = 0; k0 < K; k0 += 32) {
        const int ka = k0 + lg * 8;
        bf16x8 a0, a1;
        if constexpr (A_FP32) {
            const float* A = (const float*)Aptr;
            const float* p0 = A + (size_t)r0c * K + ka;
            const float* p1 = A + (size_t)r1c * K + ka;
            float4 u0 = *(const float4*)p0, v0 = *(const float4*)(p0 + 4);
            float4 u1 = *(const float4*)p1, v1 = *(const float4*)(p1 + 4);
            a0[0] = (__bf16)u0.x; a0[1] = (__bf16)u0.y; a0[2] = (__bf16)u0.z; a0[3] = (__bf16)u0.w;
            a0[4] = (__bf16)v0.x; a0[5] = (__bf16)v0.y; a0[6] = (__bf16)v0.z; a0[7] = (__bf16)v0.w;
            a1[0] = (__bf16)u1.x; a1[1] = (__bf16)u1.y; a1[2] = (__bf16)u1.z; a1[3] = (__bf16)u1.w;
            a1[4] = (__bf16)v1.x; a1[5] = (__bf16)v1.y; a1[6] = (__bf16)v1.z; a1[7] = (__bf16)v1.w;
        } else {
            const uint16_t* A = (const uint16_t*)Aptr;
            a0 = *reinterpret_cast<const bf16x8*>(A + (size_t)r0c * K + ka);
            a1 = *reinterpret_cast<const bf16x8*>(A + (size_t)r1c * K + ka);
        }
#pragma unroll
        for (int ct = 0; ct < NT; ++ct) {
            bf16x8 b = *reinterpret_cast<const bf16x8*>(Wt + (size_t)(ct * 16 + lr) * K + ka);
            acc[0][ct] = __builtin_amdgcn_mfma_f32_16x16x32_bf16(a0, b, acc[0][ct], 0, 0, 0);
            acc[1][ct] = __builtin_amdgcn_mfma_f32_16x16x32_bf16(a1, b, acc[1][ct], 0, 0, 0);
        }
    }

    float bv[NT];
    if constexpr (BIAS) {
#pragma unroll
        for (int ct = 0; ct < NT; ++ct) bv[ct] = bias[ct * 16 + lr];
    }

#pragma unroll
    for (int t = 0; t < 2; ++t) {
#pragma unroll
        for (int i = 0; i < 4; ++i) {
            int rr = rbase + t * 16 + lg * 4 + i;
            if (rr < M) {
#pragma unroll
                for (int ct = 0; ct < NT; ++ct) {
                    float v = acc[t][ct][i];
                    if constexpr (BIAS) v += bv[ct];
                    size_t o = (size_t)rr * NOUT + ct * 16 + lr;
                    if constexpr (OUT_F32) outF[o] = v;
                    if constexpr (OUT_BF16) outB[o] = f2bf(v);
                }
            }
        }
    }
}

// ---------------- aggregation + bias + tanh + rezero ----------------
// one wave per node; lane handles 2 features (4B bf16 pair per gathered row).
// Afp[d] = beta*Afp[d] + alpha*tanh( dd*( sum_e dinv[s]*B[s] + dd*B[d] ) + b )
// also writes Abf (bf16 copy) for the next GEMM's A operand.

__global__ __launch_bounds__(256) void agg_kernel(
    const uint16_t* __restrict__ B, float* __restrict__ Afp,
    uint16_t* __restrict__ Abf,
    const float* __restrict__ dinv, const int* __restrict__ off,
    const int* __restrict__ csr, const float* __restrict__ bconv,
    const float* __restrict__ alpha, const float* __restrict__ beta, int n)
{
    int gid = blockIdx.x * 256 + threadIdx.x;
    int d = gid >> 6;
    int lane = threadIdx.x & 63;
    if (d >= n) return;

    const int c0 = lane * 2;
    float dd = dinv[d];
    int s0 = off[d], s1 = off[d + 1];

    float ax = 0.f, ay = 0.f;
    for (int j = s0; j < s1; ++j) {
        int s = csr[j];
        float w = dinv[s];
        uint32_t u = *(const uint32_t*)(B + (size_t)s * K + c0);
        ax += w * blo(u);
        ay += w * bhi(u);
    }
    {   // self loop
        uint32_t u = *(const uint32_t*)(B + (size_t)d * K + c0);
        ax += dd * blo(u);
        ay += dd * bhi(u);
    }
    float al = alpha[0], be = beta[0];
    float2 bb = *(const float2*)(bconv + c0);
    float2 inp = *(const float2*)(Afp + (size_t)d * K + c0);
    float ox = be * inp.x + al * tanhf(dd * ax + bb.x);
    float oy = be * inp.y + al * tanhf(dd * ay + bb.y);
    *(float2*)(Afp + (size_t)d * K + c0) = make_float2(ox, oy);
    uint32_t pk = ((uint32_t)f2bf(oy) << 16) | (uint32_t)f2bf(ox);
    *(uint32_t*)(Abf + (size_t)d * K + c0) = pk;
}

// ---------------- log_softmax over 64 cols, in place, one wave per row --------

__global__ __launch_bounds__(256) void lsm_kernel(float* __restrict__ out, int n) {
    int gid = blockIdx.x * 256 + threadIdx.x;
    int row = gid >> 6;
    int lane = threadIdx.x & 63;
    if (row >= n) return;
    float* p = out + (size_t)row * 64 + lane;
    float v = *p;
    float m = v;
#pragma unroll
    for (int o = 32; o > 0; o >>= 1) m = fmaxf(m, __shfl_xor(m, o));
    float e = expf(v - m);
    float s = e;
#pragma unroll
    for (int o = 32; o > 0; o >>= 1) s += __shfl_xor(s, o);
    *p = v - m - logf(s);
}

// ---------------------------------------------------------------------------

extern "C" void kernel_launch(void* const* d_in, const int* in_sizes, int n_in,
                              void* d_out, int out_size, void* d_ws, size_t ws_size,
                              hipStream_t stream)
{
    const float* x      = (const float*)d_in[0];
    const int*   ei     = (const int*)d_in[1];
    const float* W_in   = (const float*)d_in[2];
    const float* b_in   = (const float*)d_in[3];
    const float* W_conv = (const float*)d_in[4];
    const float* b_conv = (const float*)d_in[5];
    const float* alpha  = (const float*)d_in[6];
    const float* beta   = (const float*)d_in[7];
    const float* W_out  = (const float*)d_in[8];
    const float* b_out  = (const float*)d_in[9];
    float* out = (float*)d_out;

    const int N = in_sizes[0] / K;   // 100000
    const int E = in_sizes[1] / 2;   // 1600000
    const int L = in_sizes[6];       // 4

    const int* src = ei;
    const int* dst = ei + E;

    // workspace carve (all 16B-aligned by construction)
    char* p = (char*)d_ws;
    float* Afp = (float*)p;            p += (size_t)N * K * sizeof(float);     // 51.2 MB
    uint16_t* Abf = (uint16_t*)p;      p += (size_t)N * K * sizeof(uint16_t);  // 25.6 MB
    uint16_t* Bbf = (uint16_t*)p;      p += (size_t)N * K * sizeof(uint16_t);  // 25.6 MB
    uint16_t* Wt_in = (uint16_t*)p;    p += (size_t)K * K * sizeof(uint16_t);
    uint16_t* Wt_conv = (uint16_t*)p;  p += (size_t)4 * K * K * sizeof(uint16_t);
    uint16_t* Wt_out = (uint16_t*)p;   p += (size_t)64 * K * sizeof(uint16_t);
    float* dinv = (float*)p;           p += (size_t)N * sizeof(float);
    int* cnt = (int*)p;                p += (size_t)N * sizeof(int);
    int* off = (int*)p;                p += (size_t)(N + 1) * sizeof(int);
    int* cur = (int*)p;                p += (size_t)N * sizeof(int);
    int* csr = (int*)p;                p += (size_t)E * sizeof(int);
    int* bsum = (int*)p;

    const int nb = (N + 255) / 256;

    hipMemsetAsync(cnt, 0, (size_t)N * sizeof(int), stream);
    count_kernel<<<(E + 255) / 256, 256, 0, stream>>>(dst, cnt, E);
    scan_partial<<<nb, 256, 0, stream>>>(cnt, bsum, N);
    scan_bsum<<<1, 512, 0, stream>>>(bsum, nb);
    scan_final<<<nb, 256, 0, stream>>>(cnt, bsum, off, N);
    dinv_cur_kernel<<<(N + 255) / 256, 256, 0, stream>>>(cnt, off, dinv, cur, N);
    fill_kernel<<<(E + 255) / 256, 256, 0, stream>>>(src, dst, cur, csr, E);

    // weight convert+transpose (tiny)
    wconv_kernel<<<(K * K + 255) / 256, 256, 0, stream>>>(W_in, Wt_in, K);
    for (int l = 0; l < L; ++l)
        wconv_kernel<<<(K * K + 255) / 256, 256, 0, stream>>>(
            W_conv + (size_t)l * K * K, Wt_conv + (size_t)l * K * K, K);
    wconv_kernel<<<(K * 64 + 255) / 256, 256, 0, stream>>>(W_out, Wt_out, 64);

    const int gblocks = (N + 127) / 128;
    // h0 = x @ W_in + b_in  (fp32 x converted in-kernel; writes fp32 + bf16)
    mfma_gemm<128, true, true, true, true><<<gblocks, 256, 0, stream>>>(
        x, Wt_in, b_in, Afp, Abf, N);
    for (int l = 0; l < L; ++l) {
        // Bbf = bf16(Abf @ Wc)
        mfma_gemm<128, false, false, false, true><<<gblocks, 256, 0, stream>>>(
            Abf, Wt_conv + (size_t)l * K * K, nullptr, nullptr, Bbf, N);
        agg_kernel<<<(N * 64 + 255) / 256, 256, 0, stream>>>(
            Bbf, Afp, Abf, dinv, off, csr, b_conv + (size_t)l * K, alpha + l, beta + l, N);
    }
    // logits = Abf @ W_out + b_out (fp32 to d_out)
    mfma_gemm<64, true, false, true, false><<<gblocks, 256, 0, stream>>>(
        Abf, Wt_out, b_out, out, nullptr, N);
    lsm_kernel<<<(N + 3) / 4, 256, 0, stream>>>(out, N);
}

// Round 4
// 741.101 us; speedup vs baseline: 1.9195x; 1.5011x over previous
//
#include <hip/hip_runtime.h>
#include <cstdint>
#include <cstddef>

// ---------------------------------------------------------------------------
// RezeroGCN round 3 (resubmit after infra timeout): latency-pipelined gather
// aggregation (shfl-broadcast edge indices + 8-deep independent row gathers),
// bf16 MFMA GEMMs, log_softmax fused into the output GEMM.
// ---------------------------------------------------------------------------

constexpr int K = 128;  // IN_C == HID == 128

typedef __bf16 bf16x8 __attribute__((ext_vector_type(8)));
typedef float f32x4 __attribute__((ext_vector_type(4)));

__device__ inline uint16_t f2bf(float f) {
    union { float f; uint32_t u; } c; c.f = f;
    uint32_t r = (c.u + 0x7fffu + ((c.u >> 16) & 1u)) >> 16;
    return (uint16_t)r;
}
__device__ inline float blo(uint32_t u) { union { uint32_t i; float f; } c; c.i = u << 16; return c.f; }
__device__ inline float bhi(uint32_t u) { union { uint32_t i; float f; } c; c.i = u & 0xffff0000u; return c.f; }

// ---------------- degree / CSR build ----------------

__global__ void count_kernel(const int* __restrict__ dst, int* __restrict__ cnt, int E) {
    int e = blockIdx.x * 256 + threadIdx.x;
    if (e < E) atomicAdd(&cnt[dst[e]], 1);
}

__global__ void scan_partial(const int* __restrict__ cnt, int* __restrict__ bsum, int n) {
    __shared__ int sdata[256];
    int i = blockIdx.x * 256 + threadIdx.x;
    sdata[threadIdx.x] = (i < n) ? cnt[i] : 0;
    __syncthreads();
    for (int o = 128; o > 0; o >>= 1) {
        if (threadIdx.x < o) sdata[threadIdx.x] += sdata[threadIdx.x + o];
        __syncthreads();
    }
    if (threadIdx.x == 0) bsum[blockIdx.x] = sdata[0];
}

__global__ void scan_bsum(int* __restrict__ bsum, int nb) {
    __shared__ int buf[512];
    int t = threadIdx.x;
    int v = (t < nb) ? bsum[t] : 0;
    buf[t] = v;
    __syncthreads();
    for (int o = 1; o < 512; o <<= 1) {
        int add = (t >= o) ? buf[t - o] : 0;
        __syncthreads();
        buf[t] += add;
        __syncthreads();
    }
    if (t < nb) bsum[t] = buf[t] - v;  // exclusive
}

// also emits dinv and cur (fused epilogue)
__global__ void scan_final(const int* __restrict__ cnt, const int* __restrict__ bsum,
                           int* __restrict__ off, float* __restrict__ dinv,
                           int* __restrict__ cur, int n) {
    __shared__ int buf[256];
    int t = threadIdx.x;
    int i = blockIdx.x * 256 + t;
    int v = (i < n) ? cnt[i] : 0;
    buf[t] = v;
    __syncthreads();
    for (int o = 1; o < 256; o <<= 1) {
        int add = (t >= o) ? buf[t - o] : 0;
        __syncthreads();
        buf[t] += add;
        __syncthreads();
    }
    int incl = buf[t];
    int base = bsum[blockIdx.x];
    if (i < n) {
        int o = base + incl - v;
        off[i] = o;
        cur[i] = o;
        dinv[i] = rsqrtf((float)v + 1.0f);  // +1 self-loop
    }
    if (i == n - 1) off[n] = base + incl;
}

__global__ void fill_kernel(const int* __restrict__ src, const int* __restrict__ dst,
                            int* __restrict__ cur, int* __restrict__ csr, int E) {
    int e = blockIdx.x * 256 + threadIdx.x;
    if (e < E) {
        int p = atomicAdd(&cur[dst[e]], 1);
        csr[p] = src[e];
    }
}

// ---------------- all weight transposes in one launch ----------------
// Tin[c][k]=Win[k][c]; Tc[l][c][k]=Wc[l][k][c]; To[c][k]=Wo[k][c]

__global__ void wconv_all(const float* __restrict__ Win, const float* __restrict__ Wc,
                          const float* __restrict__ Wo, uint16_t* __restrict__ Tin,
                          uint16_t* __restrict__ Tc, uint16_t* __restrict__ To) {
    int idx = blockIdx.x * 256 + threadIdx.x;
    if (idx < 16384) {
        int c = idx >> 7, k = idx & 127;
        Tin[idx] = f2bf(Win[k * 128 + c]);
    } else if (idx < 81920) {
        int t = idx - 16384;
        int l = t >> 14, li = t & 16383;
        int c = li >> 7, k = li & 127;
        Tc[t] = f2bf(Wc[l * 16384 + k * 128 + c]);
    } else if (idx < 90112) {
        int t = idx - 81920;
        int c = t >> 7, k = t & 127;
        To[t] = f2bf(Wo[k * 64 + c]);
    }
}

// ---------------- MFMA GEMM: out[M,NOUT] = A[M,128] @ Wt^T (+bias) (+lsm) --------
// 256 thr = 4 waves; wave computes 32 rows x NOUT. 16x16x32 bf16 MFMA, fp32 acc.
// D frag: lane l, reg i -> row (l>>4)*4 + i, col (l&15)  [verified round 2]

template <int NOUT, bool BIAS, bool A_FP32, bool OUT_F32, bool OUT_BF16, bool LSM>
__global__ __launch_bounds__(256) void mfma_gemm(
    const void* __restrict__ Aptr, const uint16_t* __restrict__ Wt,
    const float* __restrict__ bias, float* __restrict__ outF,
    uint16_t* __restrict__ outB, int M)
{
    constexpr int NT = NOUT / 16;
    const int tid = threadIdx.x;
    const int w = tid >> 6;
    const int l = tid & 63;
    const int lg = l >> 4;   // k-group
    const int lr = l & 15;   // row-in-tile (A) / col-in-tile (B,D)
    const int rbase = blockIdx.x * 128 + w * 32;
    const int r0c = min(rbase + lr, M - 1);
    const int r1c = min(rbase + 16 + lr, M - 1);

    f32x4 acc[2][NT] = {};

    for (int k0 = 0; k0 < K; k0 += 32) {
        const int ka = k0 + lg * 8;
        bf16x8 a0, a1;
        if constexpr (A_FP32) {
            const float* A = (const float*)Aptr;
            const float* p0 = A + (size_t)r0c * K + ka;
            const float* p1 = A + (size_t)r1c * K + ka;
            float4 u0 = *(const float4*)p0, v0 = *(const float4*)(p0 + 4);
            float4 u1 = *(const float4*)p1, v1 = *(const float4*)(p1 + 4);
            a0[0] = (__bf16)u0.x; a0[1] = (__bf16)u0.y; a0[2] = (__bf16)u0.z; a0[3] = (__bf16)u0.w;
            a0[4] = (__bf16)v0.x; a0[5] = (__bf16)v0.y; a0[6] = (__bf16)v0.z; a0[7] = (__bf16)v0.w;
            a1[0] = (__bf16)u1.x; a1[1] = (__bf16)u1.y; a1[2] = (__bf16)u1.z; a1[3] = (__bf16)u1.w;
            a1[4] = (__bf16)v1.x; a1[5] = (__bf16)v1.y; a1[6] = (__bf16)v1.z; a1[7] = (__bf16)v1.w;
        } else {
            const uint16_t* A = (const uint16_t*)Aptr;
            a0 = *reinterpret_cast<const bf16x8*>(A + (size_t)r0c * K + ka);
            a1 = *reinterpret_cast<const bf16x8*>(A + (size_t)r1c * K + ka);
        }
#pragma unroll
        for (int ct = 0; ct < NT; ++ct) {
            bf16x8 b = *reinterpret_cast<const bf16x8*>(Wt + (size_t)(ct * 16 + lr) * K + ka);
            acc[0][ct] = __builtin_amdgcn_mfma_f32_16x16x32_bf16(a0, b, acc[0][ct], 0, 0, 0);
            acc[1][ct] = __builtin_amdgcn_mfma_f32_16x16x32_bf16(a1, b, acc[1][ct], 0, 0, 0);
        }
    }

    float bv[NT];
    if constexpr (BIAS) {
#pragma unroll
        for (int ct = 0; ct < NT; ++ct) bv[ct] = bias[ct * 16 + lr];
    }

    if constexpr (LSM) {
        // fused log_softmax over NOUT cols; row is spread over the 16 lanes
        // sharing this lane's k-group (lg) -> reduce via xor masks 1,2,4,8.
#pragma unroll
        for (int t = 0; t < 2; ++t) {
#pragma unroll
            for (int i = 0; i < 4; ++i) {
                float v[NT];
                float m = -3.0e38f;
#pragma unroll
                for (int ct = 0; ct < NT; ++ct) {
                    v[ct] = acc[t][ct][i];
                    if constexpr (BIAS) v[ct] += bv[ct];
                    m = fmaxf(m, v[ct]);
                }
#pragma unroll
                for (int o = 8; o >= 1; o >>= 1) m = fmaxf(m, __shfl_xor(m, o));
                float s = 0.f;
#pragma unroll
                for (int ct = 0; ct < NT; ++ct) s += expf(v[ct] - m);
#pragma unroll
                for (int o = 8; o >= 1; o >>= 1) s += __shfl_xor(s, o);
                float lse = m + logf(s);
                int rr = rbase + t * 16 + lg * 4 + i;
                if (rr < M) {
#pragma unroll
                    for (int ct = 0; ct < NT; ++ct)
                        outF[(size_t)rr * NOUT + ct * 16 + lr] = v[ct] - lse;
                }
            }
        }
    } else {
#pragma unroll
        for (int t = 0; t < 2; ++t) {
#pragma unroll
            for (int i = 0; i < 4; ++i) {
                int rr = rbase + t * 16 + lg * 4 + i;
                if (rr < M) {
#pragma unroll
                    for (int ct = 0; ct < NT; ++ct) {
                        float v = acc[t][ct][i];
                        if constexpr (BIAS) v += bv[ct];
                        size_t o = (size_t)rr * NOUT + ct * 16 + lr;
                        if constexpr (OUT_F32) outF[o] = v;
                        if constexpr (OUT_BF16) outB[o] = f2bf(v);
                    }
                }
            }
        }
    }
}

// ---------------- aggregation + bias + tanh + rezero ----------------
// one wave per node; lane handles 2 features. Edge indices block-loaded per
// 64-edge chunk (1 coalesced csr read + 1 dinv gather), then broadcast via
// __shfl so the B-row gathers depend only on registers; unroll 8 keeps 8
// gathers in flight. Lanes past the segment end carry w=0 (safe clamped s).

__global__ __launch_bounds__(256) void agg_kernel(
    const uint16_t* __restrict__ B, float* __restrict__ Afp,
    uint16_t* __restrict__ Abf,
    const float* __restrict__ dinv, const int* __restrict__ off,
    const int* __restrict__ csr, const float* __restrict__ bconv,
    const float* __restrict__ alpha, const float* __restrict__ beta,
    int n, int E)
{
    int gid = blockIdx.x * 256 + threadIdx.x;
    int d = gid >> 6;
    int lane = threadIdx.x & 63;
    if (d >= n) return;

    const int c0 = lane * 2;
    float dd = dinv[d];
    int s0 = off[d], s1 = off[d + 1];

    float ax = 0.f, ay = 0.f;
    for (int j0 = s0; j0 < s1; j0 += 64) {
        int idx = j0 + lane;
        int sv = csr[min(idx, E - 1)];
        float wv = (idx < s1) ? dinv[sv] : 0.0f;
        int cnt = min(64, s1 - j0);
        for (int it = 0; it < cnt; it += 8) {
            float w[8]; uint32_t u[8];
#pragma unroll
            for (int q = 0; q < 8; ++q) {
                int s = __shfl(sv, it + q);
                w[q] = __shfl(wv, it + q);
                u[q] = *(const uint32_t*)(B + (size_t)s * K + c0);
            }
#pragma unroll
            for (int q = 0; q < 8; ++q) {
                ax += w[q] * blo(u[q]);
                ay += w[q] * bhi(u[q]);
            }
        }
    }
    {   // self loop
        uint32_t u = *(const uint32_t*)(B + (size_t)d * K + c0);
        ax += dd * blo(u);
        ay += dd * bhi(u);
    }
    float al = alpha[0], be = beta[0];
    float2 bb = *(const float2*)(bconv + c0);
    float2 inp = *(const float2*)(Afp + (size_t)d * K + c0);
    float ox = be * inp.x + al * tanhf(dd * ax + bb.x);
    float oy = be * inp.y + al * tanhf(dd * ay + bb.y);
    *(float2*)(Afp + (size_t)d * K + c0) = make_float2(ox, oy);
    uint32_t pk = ((uint32_t)f2bf(oy) << 16) | (uint32_t)f2bf(ox);
    *(uint32_t*)(Abf + (size_t)d * K + c0) = pk;
}

// ---------------------------------------------------------------------------

extern "C" void kernel_launch(void* const* d_in, const int* in_sizes, int n_in,
                              void* d_out, int out_size, void* d_ws, size_t ws_size,
                              hipStream_t stream)
{
    const float* x      = (const float*)d_in[0];
    const int*   ei     = (const int*)d_in[1];
    const float* W_in   = (const float*)d_in[2];
    const float* b_in   = (const float*)d_in[3];
    const float* W_conv = (const float*)d_in[4];
    const float* b_conv = (const float*)d_in[5];
    const float* alpha  = (const float*)d_in[6];
    const float* beta   = (const float*)d_in[7];
    const float* W_out  = (const float*)d_in[8];
    const float* b_out  = (const float*)d_in[9];
    float* out = (float*)d_out;

    const int N = in_sizes[0] / K;   // 100000
    const int E = in_sizes[1] / 2;   // 1600000
    const int L = in_sizes[6];       // 4

    const int* src = ei;
    const int* dst = ei + E;

    // workspace carve (all 16B-aligned by construction)
    char* p = (char*)d_ws;
    float* Afp = (float*)p;            p += (size_t)N * K * sizeof(float);     // 51.2 MB
    uint16_t* Abf = (uint16_t*)p;      p += (size_t)N * K * sizeof(uint16_t);  // 25.6 MB
    uint16_t* Bbf = (uint16_t*)p;      p += (size_t)N * K * sizeof(uint16_t);  // 25.6 MB
    uint16_t* Wt_in = (uint16_t*)p;    p += (size_t)K * K * sizeof(uint16_t);
    uint16_t* Wt_conv = (uint16_t*)p;  p += (size_t)4 * K * K * sizeof(uint16_t);
    uint16_t* Wt_out = (uint16_t*)p;   p += (size_t)64 * K * sizeof(uint16_t);
    float* dinv = (float*)p;           p += (size_t)N * sizeof(float);
    int* cnt = (int*)p;                p += (size_t)N * sizeof(int);
    int* off = (int*)p;                p += (size_t)(N + 1) * sizeof(int);
    int* cur = (int*)p;                p += (size_t)N * sizeof(int);
    int* csr = (int*)p;                p += (size_t)E * sizeof(int);
    int* bsum = (int*)p;

    const int nb = (N + 255) / 256;

    hipMemsetAsync(cnt, 0, (size_t)N * sizeof(int), stream);
    count_kernel<<<(E + 255) / 256, 256, 0, stream>>>(dst, cnt, E);
    scan_partial<<<nb, 256, 0, stream>>>(cnt, bsum, N);
    scan_bsum<<<1, 512, 0, stream>>>(bsum, nb);
    scan_final<<<nb, 256, 0, stream>>>(cnt, bsum, off, dinv, cur, N);
    fill_kernel<<<(E + 255) / 256, 256, 0, stream>>>(src, dst, cur, csr, E);
    wconv_all<<<(90112 + 255) / 256, 256, 0, stream>>>(
        W_in, W_conv, W_out, Wt_in, Wt_conv, Wt_out);

    const int gblocks = (N + 127) / 128;
    // h0 = x @ W_in + b_in  (fp32 x converted in-kernel; writes fp32 + bf16)
    mfma_gemm<128, true, true, true, true, false><<<gblocks, 256, 0, stream>>>(
        x, Wt_in, b_in, Afp, Abf, N);
    for (int l = 0; l < L; ++l) {
        mfma_gemm<128, false, false, false, true, false><<<gblocks, 256, 0, stream>>>(
            Abf, Wt_conv + (size_t)l * K * K, nullptr, nullptr, Bbf, N);
        agg_kernel<<<(N * 64 + 255) / 256, 256, 0, stream>>>(
            Bbf, Afp, Abf, dinv, off, csr, b_conv + (size_t)l * K,
            alpha + l, beta + l, N, E);
    }
    // logits = Abf @ W_out + b_out, fused log_softmax, fp32 to d_out
    mfma_gemm<64, true, false, true, false, true><<<gblocks, 256, 0, stream>>>(
        Abf, Wt_out, b_out, out, nullptr, N);
}

// Round 5
// 628.098 us; speedup vs baseline: 2.2648x; 1.1799x over previous
//
#include <hip/hip_runtime.h>
#include <cstdint>
#include <cstddef>

// ---------------------------------------------------------------------------
// RezeroGCN round 5: CSR build rewritten as 2-pass counting sort (LDS
// histograms, ~0.5M aggregated global atomics instead of 3.2M random ones).
// Gather-pipelined aggregation and bf16 MFMA GEMMs unchanged from round 4.
// ---------------------------------------------------------------------------

constexpr int K = 128;  // IN_C == HID == 128

typedef __bf16 bf16x8 __attribute__((ext_vector_type(8)));
typedef float f32x4 __attribute__((ext_vector_type(4)));

__device__ inline uint16_t f2bf(float f) {
    union { float f; uint32_t u; } c; c.f = f;
    uint32_t r = (c.u + 0x7fffu + ((c.u >> 16) & 1u)) >> 16;
    return (uint16_t)r;
}
__device__ inline float blo(uint32_t u) { union { uint32_t i; float f; } c; c.i = u << 16; return c.f; }
__device__ inline float bhi(uint32_t u) { union { uint32_t i; float f; } c; c.i = u & 0xffff0000u; return c.f; }

// ---------------- CSR build: 2-pass counting sort by dst ----------------
// bucket = dst >> 7  (128 nodes/bucket, 1024 buckets covers N <= 131072)

__global__ __launch_bounds__(256) void s1_hist(const int* __restrict__ dst,
                                               int* __restrict__ ghist, int E) {
    __shared__ int hist[1024];
    for (int i = threadIdx.x; i < 1024; i += 256) hist[i] = 0;
    __syncthreads();
    int stride = gridDim.x * 256;
    for (int e = blockIdx.x * 256 + threadIdx.x; e < E; e += stride)
        atomicAdd(&hist[dst[e] >> 7], 1);
    __syncthreads();
    for (int i = threadIdx.x; i < 1024; i += 256) {
        int c = hist[i];
        if (c) atomicAdd(&ghist[i], c);
    }
}

__global__ void s2_scan(const int* __restrict__ ghist, int* __restrict__ gbase,
                        int* __restrict__ gcur, int* __restrict__ off, int N, int E) {
    __shared__ int buf[1024];
    int t = threadIdx.x;
    int v = ghist[t];
    buf[t] = v;
    __syncthreads();
    for (int o = 1; o < 1024; o <<= 1) {
        int add = (t >= o) ? buf[t - o] : 0;
        __syncthreads();
        buf[t] += add;
        __syncthreads();
    }
    int ex = buf[t] - v;  // exclusive
    gbase[t] = ex;
    gcur[t] = ex;
    if (t == 1023) gbase[1024] = buf[1023];  // == E
    if (t == 0) off[N] = E;
}

// tile of 4096 edges per block; LDS hist + one global reservation per
// (block,bucket); pack (src<<7)|(dst&127) into ebuf at bucket-sorted pos.
__global__ __launch_bounds__(256) void s3_scatter(
    const int* __restrict__ src, const int* __restrict__ dst,
    int* __restrict__ gcur, int* __restrict__ ebuf, int E)
{
    __shared__ int hist[1024], base[1024], cursor[1024];
    const int t = threadIdx.x;
    const int tile = blockIdx.x * 4096;
    for (int i = t; i < 1024; i += 256) { hist[i] = 0; cursor[i] = 0; }
    __syncthreads();
    int sv[16], dv[16];
#pragma unroll
    for (int k = 0; k < 16; ++k) {
        int e = tile + k * 256 + t;
        bool ok = e < E;
        sv[k] = ok ? src[e] : -1;
        dv[k] = ok ? dst[e] : 0;
        if (ok) atomicAdd(&hist[dv[k] >> 7], 1);
    }
    __syncthreads();
    for (int i = t; i < 1024; i += 256) {
        int c = hist[i];
        base[i] = c ? atomicAdd(&gcur[i], c) : 0;
    }
    __syncthreads();
#pragma unroll
    for (int k = 0; k < 16; ++k) {
        if (sv[k] >= 0) {
            int b = dv[k] >> 7;
            int r = atomicAdd(&cursor[b], 1);
            ebuf[base[b] + r] = (sv[k] << 7) | (dv[k] & 127);
        }
    }
}

// one block per bucket: fine counting sort to node granularity.
// emits csr (src per edge, node-sorted), off, dinv. zero global atomics.
__global__ __launch_bounds__(256) void s4_finalize(
    const int* __restrict__ gbase, const int* __restrict__ ebuf,
    int* __restrict__ csr, int* __restrict__ off, float* __restrict__ dinv,
    int N, int E)
{
    __shared__ int hist[128], excl[128], cursor[128];
    const int b = blockIdx.x;
    const int t = threadIdx.x;
    const int lo = gbase[b], hi = gbase[b + 1];
    if (t < 128) hist[t] = 0;
    __syncthreads();
    for (int i = lo + t; i < hi; i += 256) atomicAdd(&hist[ebuf[i] & 127], 1);
    __syncthreads();
    if (t < 128) excl[t] = hist[t];
    __syncthreads();
    for (int o = 1; o < 128; o <<= 1) {
        int v = (t < 128 && t >= o) ? excl[t - o] : 0;
        __syncthreads();
        if (t < 128) excl[t] += v;
        __syncthreads();
    }
    if (t < 128) {
        int node = b * 128 + t;
        int ex = excl[t] - hist[t];  // exclusive within bucket
        cursor[t] = ex;
        if (node < N) {
            off[node] = lo + ex;
            dinv[node] = rsqrtf((float)hist[t] + 1.0f);  // +1 self-loop
        }
    }
    __syncthreads();
    for (int i = lo + t; i < hi; i += 256) {
        int v = ebuf[i];
        int r = atomicAdd(&cursor[v & 127], 1);
        csr[lo + r] = v >> 7;
    }
}

// ---------------- all weight transposes in one launch ----------------

__global__ void wconv_all(const float* __restrict__ Win, const float* __restrict__ Wc,
                          const float* __restrict__ Wo, uint16_t* __restrict__ Tin,
                          uint16_t* __restrict__ Tc, uint16_t* __restrict__ To) {
    int idx = blockIdx.x * 256 + threadIdx.x;
    if (idx < 16384) {
        int c = idx >> 7, k = idx & 127;
        Tin[idx] = f2bf(Win[k * 128 + c]);
    } else if (idx < 81920) {
        int t = idx - 16384;
        int l = t >> 14, li = t & 16383;
        int c = li >> 7, k = li & 127;
        Tc[t] = f2bf(Wc[l * 16384 + k * 128 + c]);
    } else if (idx < 90112) {
        int t = idx - 81920;
        int c = t >> 7, k = t & 127;
        To[t] = f2bf(Wo[k * 64 + c]);
    }
}

// ---------------- MFMA GEMM: out[M,NOUT] = A[M,128] @ Wt^T (+bias) (+lsm) --------
// 256 thr = 4 waves; wave computes 32 rows x NOUT. 16x16x32 bf16 MFMA, fp32 acc.
// D frag: lane l, reg i -> row (l>>4)*4 + i, col (l&15)  [verified round 2]

template <int NOUT, bool BIAS, bool A_FP32, bool OUT_F32, bool OUT_BF16, bool LSM>
__global__ __launch_bounds__(256) void mfma_gemm(
    const void* __restrict__ Aptr, const uint16_t* __restrict__ Wt,
    const float* __restrict__ bias, float* __restrict__ outF,
    uint16_t* __restrict__ outB, int M)
{
    constexpr int NT = NOUT / 16;
    const int tid = threadIdx.x;
    const int w = tid >> 6;
    const int l = tid & 63;
    const int lg = l >> 4;   // k-group
    const int lr = l & 15;   // row-in-tile (A) / col-in-tile (B,D)
    const int rbase = blockIdx.x * 128 + w * 32;
    const int r0c = min(rbase + lr, M - 1);
    const int r1c = min(rbase + 16 + lr, M - 1);

    f32x4 acc[2][NT] = {};

    for (int k0 = 0; k0 < K; k0 += 32) {
        const int ka = k0 + lg * 8;
        bf16x8 a0, a1;
        if constexpr (A_FP32) {
            const float* A = (const float*)Aptr;
            const float* p0 = A + (size_t)r0c * K + ka;
            const float* p1 = A + (size_t)r1c * K + ka;
            float4 u0 = *(const float4*)p0, v0 = *(const float4*)(p0 + 4);
            float4 u1 = *(const float4*)p1, v1 = *(const float4*)(p1 + 4);
            a0[0] = (__bf16)u0.x; a0[1] = (__bf16)u0.y; a0[2] = (__bf16)u0.z; a0[3] = (__bf16)u0.w;
            a0[4] = (__bf16)v0.x; a0[5] = (__bf16)v0.y; a0[6] = (__bf16)v0.z; a0[7] = (__bf16)v0.w;
            a1[0] = (__bf16)u1.x; a1[1] = (__bf16)u1.y; a1[2] = (__bf16)u1.z; a1[3] = (__bf16)u1.w;
            a1[4] = (__bf16)v1.x; a1[5] = (__bf16)v1.y; a1[6] = (__bf16)v1.z; a1[7] = (__bf16)v1.w;
        } else {
            const uint16_t* A = (const uint16_t*)Aptr;
            a0 = *reinterpret_cast<const bf16x8*>(A + (size_t)r0c * K + ka);
            a1 = *reinterpret_cast<const bf16x8*>(A + (size_t)r1c * K + ka);
        }
#pragma unroll
        for (int ct = 0; ct < NT; ++ct) {
            bf16x8 b = *reinterpret_cast<const bf16x8*>(Wt + (size_t)(ct * 16 + lr) * K + ka);
            acc[0][ct] = __builtin_amdgcn_mfma_f32_16x16x32_bf16(a0, b, acc[0][ct], 0, 0, 0);
            acc[1][ct] = __builtin_amdgcn_mfma_f32_16x16x32_bf16(a1, b, acc[1][ct], 0, 0, 0);
        }
    }

    float bv[NT];
    if constexpr (BIAS) {
#pragma unroll
        for (int ct = 0; ct < NT; ++ct) bv[ct] = bias[ct * 16 + lr];
    }

    if constexpr (LSM) {
#pragma unroll
        for (int t = 0; t < 2; ++t) {
#pragma unroll
            for (int i = 0; i < 4; ++i) {
                float v[NT];
                float m = -3.0e38f;
#pragma unroll
                for (int ct = 0; ct < NT; ++ct) {
                    v[ct] = acc[t][ct][i];
                    if constexpr (BIAS) v[ct] += bv[ct];
                    m = fmaxf(m, v[ct]);
                }
#pragma unroll
                for (int o = 8; o >= 1; o >>= 1) m = fmaxf(m, __shfl_xor(m, o));
                float s = 0.f;
#pragma unroll
                for (int ct = 0; ct < NT; ++ct) s += expf(v[ct] - m);
#pragma unroll
                for (int o = 8; o >= 1; o >>= 1) s += __shfl_xor(s, o);
                float lse = m + logf(s);
                int rr = rbase + t * 16 + lg * 4 + i;
                if (rr < M) {
#pragma unroll
                    for (int ct = 0; ct < NT; ++ct)
                        outF[(size_t)rr * NOUT + ct * 16 + lr] = v[ct] - lse;
                }
            }
        }
    } else {
#pragma unroll
        for (int t = 0; t < 2; ++t) {
#pragma unroll
            for (int i = 0; i < 4; ++i) {
                int rr = rbase + t * 16 + lg * 4 + i;
                if (rr < M) {
#pragma unroll
                    for (int ct = 0; ct < NT; ++ct) {
                        float v = acc[t][ct][i];
                        if constexpr (BIAS) v += bv[ct];
                        size_t o = (size_t)rr * NOUT + ct * 16 + lr;
                        if constexpr (OUT_F32) outF[o] = v;
                        if constexpr (OUT_BF16) outB[o] = f2bf(v);
                    }
                }
            }
        }
    }
}

// ---------------- aggregation + bias + tanh + rezero ----------------
// one wave per node; lane handles 2 features. Edge indices block-loaded per
// 64-edge chunk, broadcast via __shfl; 8 independent row gathers in flight.

__global__ __launch_bounds__(256) void agg_kernel(
    const uint16_t* __restrict__ B, float* __restrict__ Afp,
    uint16_t* __restrict__ Abf,
    const float* __restrict__ dinv, const int* __restrict__ off,
    const int* __restrict__ csr, const float* __restrict__ bconv,
    const float* __restrict__ alpha, const float* __restrict__ beta,
    int n, int E)
{
    int gid = blockIdx.x * 256 + threadIdx.x;
    int d = gid >> 6;
    int lane = threadIdx.x & 63;
    if (d >= n) return;

    const int c0 = lane * 2;
    float dd = dinv[d];
    int s0 = off[d], s1 = off[d + 1];

    float ax = 0.f, ay = 0.f;
    for (int j0 = s0; j0 < s1; j0 += 64) {
        int idx = j0 + lane;
        int sv = csr[min(idx, E - 1)];
        float wv = (idx < s1) ? dinv[sv] : 0.0f;
        int cnt = min(64, s1 - j0);
        for (int it = 0; it < cnt; it += 8) {
            float w[8]; uint32_t u[8];
#pragma unroll
            for (int q = 0; q < 8; ++q) {
                int s = __shfl(sv, it + q);
                w[q] = __shfl(wv, it + q);
                u[q] = *(const uint32_t*)(B + (size_t)s * K + c0);
            }
#pragma unroll
            for (int q = 0; q < 8; ++q) {
                ax += w[q] * blo(u[q]);
                ay += w[q] * bhi(u[q]);
            }
        }
    }
    {   // self loop
        uint32_t u = *(const uint32_t*)(B + (size_t)d * K + c0);
        ax += dd * blo(u);
        ay += dd * bhi(u);
    }
    float al = alpha[0], be = beta[0];
    float2 bb = *(const float2*)(bconv + c0);
    float2 inp = *(const float2*)(Afp + (size_t)d * K + c0);
    float ox = be * inp.x + al * tanhf(dd * ax + bb.x);
    float oy = be * inp.y + al * tanhf(dd * ay + bb.y);
    *(float2*)(Afp + (size_t)d * K + c0) = make_float2(ox, oy);
    uint32_t pk = ((uint32_t)f2bf(oy) << 16) | (uint32_t)f2bf(ox);
    *(uint32_t*)(Abf + (size_t)d * K + c0) = pk;
}

// ---------------------------------------------------------------------------

extern "C" void kernel_launch(void* const* d_in, const int* in_sizes, int n_in,
                              void* d_out, int out_size, void* d_ws, size_t ws_size,
                              hipStream_t stream)
{
    const float* x      = (const float*)d_in[0];
    const int*   ei     = (const int*)d_in[1];
    const float* W_in   = (const float*)d_in[2];
    const float* b_in   = (const float*)d_in[3];
    const float* W_conv = (const float*)d_in[4];
    const float* b_conv = (const float*)d_in[5];
    const float* alpha  = (const float*)d_in[6];
    const float* beta   = (const float*)d_in[7];
    const float* W_out  = (const float*)d_in[8];
    const float* b_out  = (const float*)d_in[9];
    float* out = (float*)d_out;

    const int N = in_sizes[0] / K;   // 100000
    const int E = in_sizes[1] / 2;   // 1600000
    const int L = in_sizes[6];       // 4

    const int* src = ei;
    const int* dst = ei + E;

    // workspace carve
    char* p = (char*)d_ws;
    float* Afp = (float*)p;            p += (size_t)N * K * sizeof(float);     // 51.2 MB
    uint16_t* Abf = (uint16_t*)p;      p += (size_t)N * K * sizeof(uint16_t);  // 25.6 MB
    uint16_t* Bbf = (uint16_t*)p;      p += (size_t)N * K * sizeof(uint16_t);  // 25.6 MB
    uint16_t* Wt_in = (uint16_t*)p;    p += (size_t)K * K * sizeof(uint16_t);
    uint16_t* Wt_conv = (uint16_t*)p;  p += (size_t)4 * K * K * sizeof(uint16_t);
    uint16_t* Wt_out = (uint16_t*)p;   p += (size_t)64 * K * sizeof(uint16_t);
    float* dinv = (float*)p;           p += (size_t)N * sizeof(float);
    int* off = (int*)p;                p += (size_t)(N + 1) * sizeof(int);
    int* csr = (int*)p;                p += (size_t)E * sizeof(int);
    int* ghist = (int*)p;              p += 1024 * sizeof(int);
    int* gbase = (int*)p;              p += 1025 * sizeof(int);
    int* gcur = (int*)p;               p += 1024 * sizeof(int);
    // ebuf aliases Bbf: only live during the CSR build, before any GEMM.
    int* ebuf = (int*)Bbf;

    // ---- CSR build (counting sort by dst) ----
    hipMemsetAsync(ghist, 0, 1024 * sizeof(int), stream);
    s1_hist<<<256, 256, 0, stream>>>(dst, ghist, E);
    s2_scan<<<1, 1024, 0, stream>>>(ghist, gbase, gcur, off, N, E);
    s3_scatter<<<(E + 4095) / 4096, 256, 0, stream>>>(src, dst, gcur, ebuf, E);
    s4_finalize<<<(N + 127) / 128, 256, 0, stream>>>(gbase, ebuf, csr, off, dinv, N, E);

    wconv_all<<<(90112 + 255) / 256, 256, 0, stream>>>(
        W_in, W_conv, W_out, Wt_in, Wt_conv, Wt_out);

    const int gblocks = (N + 127) / 128;
    // h0 = x @ W_in + b_in  (fp32 x converted in-kernel; writes fp32 + bf16)
    mfma_gemm<128, true, true, true, true, false><<<gblocks, 256, 0, stream>>>(
        x, Wt_in, b_in, Afp, Abf, N);
    for (int l = 0; l < L; ++l) {
        mfma_gemm<128, false, false, false, true, false><<<gblocks, 256, 0, stream>>>(
            Abf, Wt_conv + (size_t)l * K * K, nullptr, nullptr, Bbf, N);
        agg_kernel<<<(N * 64 + 255) / 256, 256, 0, stream>>>(
            Bbf, Afp, Abf, dinv, off, csr, b_conv + (size_t)l * K,
            alpha + l, beta + l, N, E);
    }
    // logits = Abf @ W_out + b_out, fused log_softmax, fp32 to d_out
    mfma_gemm<64, true, false, true, false, true><<<gblocks, 256, 0, stream>>>(
        Abf, Wt_out, b_out, out, nullptr, N);
}

// Round 6
// 575.843 us; speedup vs baseline: 2.4704x; 1.0907x over previous
//
#include <hip/hip_runtime.h>
#include <cstdint>
#include <cstddef>

// ---------------------------------------------------------------------------
// RezeroGCN round 6: agg slimmed — messages pre-scaled by dinv[src] in the
// GEMM epilogue (unweighted sum in agg), bf16-only residual (no fp32 array),
// dual-row 8B/lane gathers (half-wave per edge). CSR counting sort + bf16
// MFMA GEMMs + fused log_softmax unchanged from round 5.
// ---------------------------------------------------------------------------

constexpr int K = 128;  // IN_C == HID == 128

typedef __bf16 bf16x8 __attribute__((ext_vector_type(8)));
typedef float f32x4 __attribute__((ext_vector_type(4)));

__device__ inline uint16_t f2bf(float f) {
    union { float f; uint32_t u; } c; c.f = f;
    uint32_t r = (c.u + 0x7fffu + ((c.u >> 16) & 1u)) >> 16;
    return (uint16_t)r;
}
__device__ inline float blo(uint32_t u) { union { uint32_t i; float f; } c; c.i = u << 16; return c.f; }
__device__ inline float bhi(uint32_t u) { union { uint32_t i; float f; } c; c.i = u & 0xffff0000u; return c.f; }

// ---------------- CSR build: 2-pass counting sort by dst ----------------
// bucket = dst >> 7  (128 nodes/bucket, 1024 buckets covers N <= 131072)

__global__ __launch_bounds__(256) void s1_hist(const int* __restrict__ dst,
                                               int* __restrict__ ghist, int E) {
    __shared__ int hist[1024];
    for (int i = threadIdx.x; i < 1024; i += 256) hist[i] = 0;
    __syncthreads();
    int stride = gridDim.x * 256;
    for (int e = blockIdx.x * 256 + threadIdx.x; e < E; e += stride)
        atomicAdd(&hist[dst[e] >> 7], 1);
    __syncthreads();
    for (int i = threadIdx.x; i < 1024; i += 256) {
        int c = hist[i];
        if (c) atomicAdd(&ghist[i], c);
    }
}

__global__ void s2_scan(const int* __restrict__ ghist, int* __restrict__ gbase,
                        int* __restrict__ gcur, int* __restrict__ off, int N, int E) {
    __shared__ int buf[1024];
    int t = threadIdx.x;
    int v = ghist[t];
    buf[t] = v;
    __syncthreads();
    for (int o = 1; o < 1024; o <<= 1) {
        int add = (t >= o) ? buf[t - o] : 0;
        __syncthreads();
        buf[t] += add;
        __syncthreads();
    }
    int ex = buf[t] - v;  // exclusive
    gbase[t] = ex;
    gcur[t] = ex;
    if (t == 1023) gbase[1024] = buf[1023];  // == E
    if (t == 0) off[N] = E;
}

__global__ __launch_bounds__(256) void s3_scatter(
    const int* __restrict__ src, const int* __restrict__ dst,
    int* __restrict__ gcur, int* __restrict__ ebuf, int E)
{
    __shared__ int hist[1024], base[1024], cursor[1024];
    const int t = threadIdx.x;
    const int tile = blockIdx.x * 4096;
    for (int i = t; i < 1024; i += 256) { hist[i] = 0; cursor[i] = 0; }
    __syncthreads();
    int sv[16], dv[16];
#pragma unroll
    for (int k = 0; k < 16; ++k) {
        int e = tile + k * 256 + t;
        bool ok = e < E;
        sv[k] = ok ? src[e] : -1;
        dv[k] = ok ? dst[e] : 0;
        if (ok) atomicAdd(&hist[dv[k] >> 7], 1);
    }
    __syncthreads();
    for (int i = t; i < 1024; i += 256) {
        int c = hist[i];
        base[i] = c ? atomicAdd(&gcur[i], c) : 0;
    }
    __syncthreads();
#pragma unroll
    for (int k = 0; k < 16; ++k) {
        if (sv[k] >= 0) {
            int b = dv[k] >> 7;
            int r = atomicAdd(&cursor[b], 1);
            ebuf[base[b] + r] = (sv[k] << 7) | (dv[k] & 127);
        }
    }
}

__global__ __launch_bounds__(256) void s4_finalize(
    const int* __restrict__ gbase, const int* __restrict__ ebuf,
    int* __restrict__ csr, int* __restrict__ off, float* __restrict__ dinv,
    int N, int E)
{
    __shared__ int hist[128], excl[128], cursor[128];
    const int b = blockIdx.x;
    const int t = threadIdx.x;
    const int lo = gbase[b], hi = gbase[b + 1];
    if (t < 128) hist[t] = 0;
    __syncthreads();
    for (int i = lo + t; i < hi; i += 256) atomicAdd(&hist[ebuf[i] & 127], 1);
    __syncthreads();
    if (t < 128) excl[t] = hist[t];
    __syncthreads();
    for (int o = 1; o < 128; o <<= 1) {
        int v = (t < 128 && t >= o) ? excl[t - o] : 0;
        __syncthreads();
        if (t < 128) excl[t] += v;
        __syncthreads();
    }
    if (t < 128) {
        int node = b * 128 + t;
        int ex = excl[t] - hist[t];
        cursor[t] = ex;
        if (node < N) {
            off[node] = lo + ex;
            dinv[node] = rsqrtf((float)hist[t] + 1.0f);  // +1 self-loop
        }
    }
    __syncthreads();
    for (int i = lo + t; i < hi; i += 256) {
        int v = ebuf[i];
        int r = atomicAdd(&cursor[v & 127], 1);
        csr[lo + r] = v >> 7;
    }
}

// ---------------- all weight transposes in one launch ----------------

__global__ void wconv_all(const float* __restrict__ Win, const float* __restrict__ Wc,
                          const float* __restrict__ Wo, uint16_t* __restrict__ Tin,
                          uint16_t* __restrict__ Tc, uint16_t* __restrict__ To) {
    int idx = blockIdx.x * 256 + threadIdx.x;
    if (idx < 16384) {
        int c = idx >> 7, k = idx & 127;
        Tin[idx] = f2bf(Win[k * 128 + c]);
    } else if (idx < 81920) {
        int t = idx - 16384;
        int l = t >> 14, li = t & 16383;
        int c = li >> 7, k = li & 127;
        Tc[t] = f2bf(Wc[l * 16384 + k * 128 + c]);
    } else if (idx < 90112) {
        int t = idx - 81920;
        int c = t >> 7, k = t & 127;
        To[t] = f2bf(Wo[k * 64 + c]);
    }
}

// ---------------- MFMA GEMM: out[M,NOUT] = A[M,128] @ Wt^T (+bias|scale) (+lsm) ----
// 256 thr = 4 waves; wave computes 32 rows x NOUT. 16x16x32 bf16 MFMA, fp32 acc.
// D frag: lane l, reg i -> row (l>>4)*4 + i, col (l&15)  [verified round 2]
// SCALE: multiply row rr by rowscale[rr] before store (dinv pre-scaling).

template <int NOUT, bool BIAS, bool A_FP32, bool OUT_F32, bool OUT_BF16, bool LSM, bool SCALE>
__global__ __launch_bounds__(256) void mfma_gemm(
    const void* __restrict__ Aptr, const uint16_t* __restrict__ Wt,
    const float* __restrict__ bias, float* __restrict__ outF,
    uint16_t* __restrict__ outB, const float* __restrict__ rowscale, int M)
{
    constexpr int NT = NOUT / 16;
    const int tid = threadIdx.x;
    const int w = tid >> 6;
    const int l = tid & 63;
    const int lg = l >> 4;   // k-group
    const int lr = l & 15;   // row-in-tile (A) / col-in-tile (B,D)
    const int rbase = blockIdx.x * 128 + w * 32;
    const int r0c = min(rbase + lr, M - 1);
    const int r1c = min(rbase + 16 + lr, M - 1);

    f32x4 acc[2][NT] = {};

    for (int k0 = 0; k0 < K; k0 += 32) {
        const int ka = k0 + lg * 8;
        bf16x8 a0, a1;
        if constexpr (A_FP32) {
            const float* A = (const float*)Aptr;
            const float* p0 = A + (size_t)r0c * K + ka;
            const float* p1 = A + (size_t)r1c * K + ka;
            float4 u0 = *(const float4*)p0, v0 = *(const float4*)(p0 + 4);
            float4 u1 = *(const float4*)p1, v1 = *(const float4*)(p1 + 4);
            a0[0] = (__bf16)u0.x; a0[1] = (__bf16)u0.y; a0[2] = (__bf16)u0.z; a0[3] = (__bf16)u0.w;
            a0[4] = (__bf16)v0.x; a0[5] = (__bf16)v0.y; a0[6] = (__bf16)v0.z; a0[7] = (__bf16)v0.w;
            a1[0] = (__bf16)u1.x; a1[1] = (__bf16)u1.y; a1[2] = (__bf16)u1.z; a1[3] = (__bf16)u1.w;
            a1[4] = (__bf16)v1.x; a1[5] = (__bf16)v1.y; a1[6] = (__bf16)v1.z; a1[7] = (__bf16)v1.w;
        } else {
            const uint16_t* A = (const uint16_t*)Aptr;
            a0 = *reinterpret_cast<const bf16x8*>(A + (size_t)r0c * K + ka);
            a1 = *reinterpret_cast<const bf16x8*>(A + (size_t)r1c * K + ka);
        }
#pragma unroll
        for (int ct = 0; ct < NT; ++ct) {
            bf16x8 b = *reinterpret_cast<const bf16x8*>(Wt + (size_t)(ct * 16 + lr) * K + ka);
            acc[0][ct] = __builtin_amdgcn_mfma_f32_16x16x32_bf16(a0, b, acc[0][ct], 0, 0, 0);
            acc[1][ct] = __builtin_amdgcn_mfma_f32_16x16x32_bf16(a1, b, acc[1][ct], 0, 0, 0);
        }
    }

    float bv[NT];
    if constexpr (BIAS) {
#pragma unroll
        for (int ct = 0; ct < NT; ++ct) bv[ct] = bias[ct * 16 + lr];
    }

    if constexpr (LSM) {
#pragma unroll
        for (int t = 0; t < 2; ++t) {
#pragma unroll
            for (int i = 0; i < 4; ++i) {
                float v[NT];
                float m = -3.0e38f;
#pragma unroll
                for (int ct = 0; ct < NT; ++ct) {
                    v[ct] = acc[t][ct][i];
                    if constexpr (BIAS) v[ct] += bv[ct];
                    m = fmaxf(m, v[ct]);
                }
#pragma unroll
                for (int o = 8; o >= 1; o >>= 1) m = fmaxf(m, __shfl_xor(m, o));
                float s = 0.f;
#pragma unroll
                for (int ct = 0; ct < NT; ++ct) s += expf(v[ct] - m);
#pragma unroll
                for (int o = 8; o >= 1; o >>= 1) s += __shfl_xor(s, o);
                float lse = m + logf(s);
                int rr = rbase + t * 16 + lg * 4 + i;
                if (rr < M) {
#pragma unroll
                    for (int ct = 0; ct < NT; ++ct)
                        outF[(size_t)rr * NOUT + ct * 16 + lr] = v[ct] - lse;
                }
            }
        }
    } else {
#pragma unroll
        for (int t = 0; t < 2; ++t) {
#pragma unroll
            for (int i = 0; i < 4; ++i) {
                int rr = rbase + t * 16 + lg * 4 + i;
                if (rr < M) {
                    float sc = 1.0f;
                    if constexpr (SCALE) sc = rowscale[rr];
#pragma unroll
                    for (int ct = 0; ct < NT; ++ct) {
                        float v = acc[t][ct][i];
                        if constexpr (BIAS) v += bv[ct];
                        if constexpr (SCALE) v *= sc;
                        size_t o = (size_t)rr * NOUT + ct * 16 + lr;
                        if constexpr (OUT_F32) outF[o] = v;
                        if constexpr (OUT_BF16) outB[o] = f2bf(v);
                    }
                }
            }
        }
    }
}

// ---------------- aggregation + bias + tanh + rezero (bf16 residual) ----------------
// one wave per node. B holds pre-scaled messages B'[s] = dinv[s]*(h@W)[s], so the
// aggregate is an unweighted sum. Half-wave 0 processes even edges, half-wave 1 odd
// edges (8B/lane = 4 features); shfl_xor(32) combines at the end.
// A[d] = bf16( beta*A[d] + alpha*tanh( dinv[d]*(sum + B'[d]) + b ) )

__global__ __launch_bounds__(256) void agg_kernel(
    const uint16_t* __restrict__ B, uint16_t* __restrict__ A,
    const float* __restrict__ dinv, const int* __restrict__ off,
    const int* __restrict__ csr, const float* __restrict__ bconv,
    const float* __restrict__ alpha, const float* __restrict__ beta,
    int n, int E)
{
    int gid = blockIdx.x * 256 + threadIdx.x;
    int d = gid >> 6;
    int lane = threadIdx.x & 63;
    if (d >= n) return;

    const int half = lane >> 5;
    const int c0 = (lane & 31) * 4;  // 4 features per lane
    float a0 = 0.f, a1 = 0.f, a2 = 0.f, a3 = 0.f;
    const int s0 = off[d], s1 = off[d + 1];
    const int deg = s1 - s0;
    const int full = deg & ~63;

    for (int j0 = s0; j0 < s0 + full; j0 += 64) {
        int sv = csr[j0 + lane];
        for (int it = 0; it < 64; it += 16) {  // 16 edges, 8 loads in flight
            uint2 u[8];
#pragma unroll
            for (int q = 0; q < 8; ++q) {
                int s = __shfl(sv, it + 2 * q + half);
                u[q] = *(const uint2*)(B + (size_t)s * K + c0);
            }
#pragma unroll
            for (int q = 0; q < 8; ++q) {
                a0 += blo(u[q].x); a1 += bhi(u[q].x);
                a2 += blo(u[q].y); a3 += bhi(u[q].y);
            }
        }
    }
    int rem = deg - full;
    if (rem) {
        int idx = s0 + full + lane;
        int sv = csr[min(idx, E - 1)];
        for (int it = 0; it < rem; it += 16) {
            uint2 u[8];
#pragma unroll
            for (int q = 0; q < 8; ++q) {
                int e = it + 2 * q + half;
                int s = __shfl(sv, e);
                if (e < rem) u[q] = *(const uint2*)(B + (size_t)s * K + c0);
                else u[q] = make_uint2(0u, 0u);
            }
#pragma unroll
            for (int q = 0; q < 8; ++q) {
                a0 += blo(u[q].x); a1 += bhi(u[q].x);
                a2 += blo(u[q].y); a3 += bhi(u[q].y);
            }
        }
    }
    // combine the two half-wave partial sums
    a0 += __shfl_xor(a0, 32); a1 += __shfl_xor(a1, 32);
    a2 += __shfl_xor(a2, 32); a3 += __shfl_xor(a3, 32);
    // self loop: B'[d] = dinv[d]*hW[d] already pre-scaled
    uint2 us = *(const uint2*)(B + (size_t)d * K + c0);
    a0 += blo(us.x); a1 += bhi(us.x); a2 += blo(us.y); a3 += bhi(us.y);

    float dd = dinv[d];
    float al = alpha[0], be = beta[0];
    float4 bb = *(const float4*)(bconv + c0);
    uint2 ip = *(const uint2*)(A + (size_t)d * K + c0);
    float o0 = be * blo(ip.x) + al * tanhf(dd * a0 + bb.x);
    float o1 = be * bhi(ip.x) + al * tanhf(dd * a1 + bb.y);
    float o2 = be * blo(ip.y) + al * tanhf(dd * a2 + bb.z);
    float o3 = be * bhi(ip.y) + al * tanhf(dd * a3 + bb.w);
    if (half == 0) {
        uint2 pk;
        pk.x = ((uint32_t)f2bf(o1) << 16) | (uint32_t)f2bf(o0);
        pk.y = ((uint32_t)f2bf(o3) << 16) | (uint32_t)f2bf(o2);
        *(uint2*)(A + (size_t)d * K + c0) = pk;
    }
}

// ---------------------------------------------------------------------------

extern "C" void kernel_launch(void* const* d_in, const int* in_sizes, int n_in,
                              void* d_out, int out_size, void* d_ws, size_t ws_size,
                              hipStream_t stream)
{
    const float* x      = (const float*)d_in[0];
    const int*   ei     = (const int*)d_in[1];
    const float* W_in   = (const float*)d_in[2];
    const float* b_in   = (const float*)d_in[3];
    const float* W_conv = (const float*)d_in[4];
    const float* b_conv = (const float*)d_in[5];
    const float* alpha  = (const float*)d_in[6];
    const float* beta   = (const float*)d_in[7];
    const float* W_out  = (const float*)d_in[8];
    const float* b_out  = (const float*)d_in[9];
    float* out = (float*)d_out;

    const int N = in_sizes[0] / K;   // 100000
    const int E = in_sizes[1] / 2;   // 1600000
    const int L = in_sizes[6];       // 4

    const int* src = ei;
    const int* dst = ei + E;

    // workspace carve (16B-aligned by construction)
    char* p = (char*)d_ws;
    uint16_t* Abf = (uint16_t*)p;      p += (size_t)N * K * sizeof(uint16_t);  // 25.6 MB
    uint16_t* Bbf = (uint16_t*)p;      p += (size_t)N * K * sizeof(uint16_t);  // 25.6 MB
    uint16_t* Wt_in = (uint16_t*)p;    p += (size_t)K * K * sizeof(uint16_t);
    uint16_t* Wt_conv = (uint16_t*)p;  p += (size_t)4 * K * K * sizeof(uint16_t);
    uint16_t* Wt_out = (uint16_t*)p;   p += (size_t)64 * K * sizeof(uint16_t);
    float* dinv = (float*)p;           p += (size_t)N * sizeof(float);
    int* off = (int*)p;                p += (size_t)(N + 1) * sizeof(int);
    int* csr = (int*)p;                p += (size_t)E * sizeof(int);
    int* ghist = (int*)p;              p += 1024 * sizeof(int);
    int* gbase = (int*)p;              p += 1025 * sizeof(int);
    int* gcur = (int*)p;               p += 1024 * sizeof(int);
    // ebuf aliases Bbf: only live during the CSR build, before any GEMM.
    int* ebuf = (int*)Bbf;

    // ---- CSR build (counting sort by dst) ----
    hipMemsetAsync(ghist, 0, 1024 * sizeof(int), stream);
    s1_hist<<<256, 256, 0, stream>>>(dst, ghist, E);
    s2_scan<<<1, 1024, 0, stream>>>(ghist, gbase, gcur, off, N, E);
    s3_scatter<<<(E + 4095) / 4096, 256, 0, stream>>>(src, dst, gcur, ebuf, E);
    s4_finalize<<<(N + 127) / 128, 256, 0, stream>>>(gbase, ebuf, csr, off, dinv, N, E);

    wconv_all<<<(90112 + 255) / 256, 256, 0, stream>>>(
        W_in, W_conv, W_out, Wt_in, Wt_conv, Wt_out);

    const int gblocks = (N + 127) / 128;
    // h0 = x @ W_in + b_in  -> Abf (bf16 residual)
    mfma_gemm<128, true, true, false, true, false, false><<<gblocks, 256, 0, stream>>>(
        x, Wt_in, b_in, nullptr, Abf, nullptr, N);
    for (int l = 0; l < L; ++l) {
        // Bbf = bf16( dinv[row] * (Abf @ Wc) )   (pre-scaled messages)
        mfma_gemm<128, false, false, false, true, false, true><<<gblocks, 256, 0, stream>>>(
            Abf, Wt_conv + (size_t)l * K * K, nullptr, nullptr, Bbf, dinv, N);
        agg_kernel<<<(N * 64 + 255) / 256, 256, 0, stream>>>(
            Bbf, Abf, dinv, off, csr, b_conv + (size_t)l * K,
            alpha + l, beta + l, N, E);
    }
    // logits = Abf @ W_out + b_out, fused log_softmax, fp32 to d_out
    mfma_gemm<64, true, false, true, false, true, false><<<gblocks, 256, 0, stream>>>(
        Abf, Wt_out, b_out, out, nullptr, nullptr, N);
}

// Round 7
// 495.946 us; speedup vs baseline: 2.8683x; 1.1611x over previous
//
#include <hip/hip_runtime.h>
#include <cstdint>
#include <cstddef>

// ---------------------------------------------------------------------------
// RezeroGCN round 7: fp8(e4m3, OCP) pre-scaled messages — 128B/row gathers
// (half the L2-miss traffic), byte-offset CSR (no 64-bit addr chain in the
// gather loop). bf16 residual + MFMA GEMMs + counting-sort CSR unchanged.
// ---------------------------------------------------------------------------

constexpr int K = 128;  // IN_C == HID == 128

typedef __bf16 bf16x8 __attribute__((ext_vector_type(8)));
typedef float f32x4 __attribute__((ext_vector_type(4)));
typedef float f32x2 __attribute__((ext_vector_type(2)));

__device__ inline uint16_t f2bf(float f) {
    union { float f; uint32_t u; } c; c.f = f;
    uint32_t r = (c.u + 0x7fffu + ((c.u >> 16) & 1u)) >> 16;
    return (uint16_t)r;
}
__device__ inline float blo(uint32_t u) { union { uint32_t i; float f; } c; c.i = u << 16; return c.f; }
__device__ inline float bhi(uint32_t u) { union { uint32_t i; float f; } c; c.i = u & 0xffff0000u; return c.f; }

// ---------------- CSR build: 2-pass counting sort by dst ----------------
// bucket = dst >> 7  (128 nodes/bucket, 1024 buckets covers N <= 131072)

__global__ __launch_bounds__(256) void s1_hist(const int* __restrict__ dst,
                                               int* __restrict__ ghist, int E) {
    __shared__ int hist[1024];
    for (int i = threadIdx.x; i < 1024; i += 256) hist[i] = 0;
    __syncthreads();
    int stride = gridDim.x * 256;
    for (int e = blockIdx.x * 256 + threadIdx.x; e < E; e += stride)
        atomicAdd(&hist[dst[e] >> 7], 1);
    __syncthreads();
    for (int i = threadIdx.x; i < 1024; i += 256) {
        int c = hist[i];
        if (c) atomicAdd(&ghist[i], c);
    }
}

__global__ void s2_scan(const int* __restrict__ ghist, int* __restrict__ gbase,
                        int* __restrict__ gcur, int* __restrict__ off, int N, int E) {
    __shared__ int buf[1024];
    int t = threadIdx.x;
    int v = ghist[t];
    buf[t] = v;
    __syncthreads();
    for (int o = 1; o < 1024; o <<= 1) {
        int add = (t >= o) ? buf[t - o] : 0;
        __syncthreads();
        buf[t] += add;
        __syncthreads();
    }
    int ex = buf[t] - v;  // exclusive
    gbase[t] = ex;
    gcur[t] = ex;
    if (t == 1023) gbase[1024] = buf[1023];  // == E
    if (t == 0) off[N] = E;
}

__global__ __launch_bounds__(256) void s3_scatter(
    const int* __restrict__ src, const int* __restrict__ dst,
    int* __restrict__ gcur, int* __restrict__ ebuf, int E)
{
    __shared__ int hist[1024], base[1024], cursor[1024];
    const int t = threadIdx.x;
    const int tile = blockIdx.x * 4096;
    for (int i = t; i < 1024; i += 256) { hist[i] = 0; cursor[i] = 0; }
    __syncthreads();
    int sv[16], dv[16];
#pragma unroll
    for (int k = 0; k < 16; ++k) {
        int e = tile + k * 256 + t;
        bool ok = e < E;
        sv[k] = ok ? src[e] : -1;
        dv[k] = ok ? dst[e] : 0;
        if (ok) atomicAdd(&hist[dv[k] >> 7], 1);
    }
    __syncthreads();
    for (int i = t; i < 1024; i += 256) {
        int c = hist[i];
        base[i] = c ? atomicAdd(&gcur[i], c) : 0;
    }
    __syncthreads();
#pragma unroll
    for (int k = 0; k < 16; ++k) {
        if (sv[k] >= 0) {
            int b = dv[k] >> 7;
            int r = atomicAdd(&cursor[b], 1);
            ebuf[base[b] + r] = (sv[k] << 7) | (dv[k] & 127);
        }
    }
}

// csr entries are BYTE offsets into the fp8 message matrix: src*128 bytes.
__global__ __launch_bounds__(256) void s4_finalize(
    const int* __restrict__ gbase, const int* __restrict__ ebuf,
    int* __restrict__ csr, int* __restrict__ off, float* __restrict__ dinv,
    int N, int E)
{
    __shared__ int hist[128], excl[128], cursor[128];
    const int b = blockIdx.x;
    const int t = threadIdx.x;
    const int lo = gbase[b], hi = gbase[b + 1];
    if (t < 128) hist[t] = 0;
    __syncthreads();
    for (int i = lo + t; i < hi; i += 256) atomicAdd(&hist[ebuf[i] & 127], 1);
    __syncthreads();
    if (t < 128) excl[t] = hist[t];
    __syncthreads();
    for (int o = 1; o < 128; o <<= 1) {
        int v = (t < 128 && t >= o) ? excl[t - o] : 0;
        __syncthreads();
        if (t < 128) excl[t] += v;
        __syncthreads();
    }
    if (t < 128) {
        int node = b * 128 + t;
        int ex = excl[t] - hist[t];
        cursor[t] = ex;
        if (node < N) {
            off[node] = lo + ex;
            dinv[node] = rsqrtf((float)hist[t] + 1.0f);  // +1 self-loop
        }
    }
    __syncthreads();
    for (int i = lo + t; i < hi; i += 256) {
        int v = ebuf[i];
        int r = atomicAdd(&cursor[v & 127], 1);
        csr[lo + r] = v & ~127;  // src<<7 == fp8-row byte offset
    }
}

// ---------------- all weight transposes in one launch ----------------

__global__ void wconv_all(const float* __restrict__ Win, const float* __restrict__ Wc,
                          const float* __restrict__ Wo, uint16_t* __restrict__ Tin,
                          uint16_t* __restrict__ Tc, uint16_t* __restrict__ To) {
    int idx = blockIdx.x * 256 + threadIdx.x;
    if (idx < 16384) {
        int c = idx >> 7, k = idx & 127;
        Tin[idx] = f2bf(Win[k * 128 + c]);
    } else if (idx < 81920) {
        int t = idx - 16384;
        int l = t >> 14, li = t & 16383;
        int c = li >> 7, k = li & 127;
        Tc[t] = f2bf(Wc[l * 16384 + k * 128 + c]);
    } else if (idx < 90112) {
        int t = idx - 81920;
        int c = t >> 7, k = t & 127;
        To[t] = f2bf(Wo[k * 64 + c]);
    }
}

// ---------------- MFMA GEMM: out[M,NOUT] = A[M,128] @ Wt^T ----------------
// OMODE 0: +bias -> bf16   (input projection)
// OMODE 1: +bias -> f32 with fused log_softmax (output projection)
// OMODE 2: *rowscale -> fp8 e4m3 (pre-scaled messages for aggregation)
// D frag: lane l, reg i -> row (l>>4)*4 + i, col (l&15)  [verified round 2]

template <int NOUT, bool A_FP32, int OMODE>
__global__ __launch_bounds__(256) void mfma_gemm(
    const void* __restrict__ Aptr, const uint16_t* __restrict__ Wt,
    const float* __restrict__ bias, float* __restrict__ outF,
    uint16_t* __restrict__ outB, uint8_t* __restrict__ outQ,
    const float* __restrict__ rowscale, int M)
{
    constexpr int NT = NOUT / 16;
    const int tid = threadIdx.x;
    const int w = tid >> 6;
    const int l = tid & 63;
    const int lg = l >> 4;   // k-group
    const int lr = l & 15;   // row-in-tile (A) / col-in-tile (B,D)
    const int rbase = blockIdx.x * 128 + w * 32;
    const int r0c = min(rbase + lr, M - 1);
    const int r1c = min(rbase + 16 + lr, M - 1);

    f32x4 acc[2][NT] = {};

    for (int k0 = 0; k0 < K; k0 += 32) {
        const int ka = k0 + lg * 8;
        bf16x8 a0, a1;
        if constexpr (A_FP32) {
            const float* A = (const float*)Aptr;
            const float* p0 = A + (size_t)r0c * K + ka;
            const float* p1 = A + (size_t)r1c * K + ka;
            float4 u0 = *(const float4*)p0, v0 = *(const float4*)(p0 + 4);
            float4 u1 = *(const float4*)p1, v1 = *(const float4*)(p1 + 4);
            a0[0] = (__bf16)u0.x; a0[1] = (__bf16)u0.y; a0[2] = (__bf16)u0.z; a0[3] = (__bf16)u0.w;
            a0[4] = (__bf16)v0.x; a0[5] = (__bf16)v0.y; a0[6] = (__bf16)v0.z; a0[7] = (__bf16)v0.w;
            a1[0] = (__bf16)u1.x; a1[1] = (__bf16)u1.y; a1[2] = (__bf16)u1.z; a1[3] = (__bf16)u1.w;
            a1[4] = (__bf16)v1.x; a1[5] = (__bf16)v1.y; a1[6] = (__bf16)v1.z; a1[7] = (__bf16)v1.w;
        } else {
            const uint16_t* A = (const uint16_t*)Aptr;
            a0 = *reinterpret_cast<const bf16x8*>(A + (size_t)r0c * K + ka);
            a1 = *reinterpret_cast<const bf16x8*>(A + (size_t)r1c * K + ka);
        }
#pragma unroll
        for (int ct = 0; ct < NT; ++ct) {
            bf16x8 b = *reinterpret_cast<const bf16x8*>(Wt + (size_t)(ct * 16 + lr) * K + ka);
            acc[0][ct] = __builtin_amdgcn_mfma_f32_16x16x32_bf16(a0, b, acc[0][ct], 0, 0, 0);
            acc[1][ct] = __builtin_amdgcn_mfma_f32_16x16x32_bf16(a1, b, acc[1][ct], 0, 0, 0);
        }
    }

    float bv[NT];
    if constexpr (OMODE == 0 || OMODE == 1) {
#pragma unroll
        for (int ct = 0; ct < NT; ++ct) bv[ct] = bias[ct * 16 + lr];
    }

    if constexpr (OMODE == 1) {
#pragma unroll
        for (int t = 0; t < 2; ++t) {
#pragma unroll
            for (int i = 0; i < 4; ++i) {
                float v[NT];
                float m = -3.0e38f;
#pragma unroll
                for (int ct = 0; ct < NT; ++ct) {
                    v[ct] = acc[t][ct][i] + bv[ct];
                    m = fmaxf(m, v[ct]);
                }
#pragma unroll
                for (int o = 8; o >= 1; o >>= 1) m = fmaxf(m, __shfl_xor(m, o));
                float s = 0.f;
#pragma unroll
                for (int ct = 0; ct < NT; ++ct) s += expf(v[ct] - m);
#pragma unroll
                for (int o = 8; o >= 1; o >>= 1) s += __shfl_xor(s, o);
                float lse = m + logf(s);
                int rr = rbase + t * 16 + lg * 4 + i;
                if (rr < M) {
#pragma unroll
                    for (int ct = 0; ct < NT; ++ct)
                        outF[(size_t)rr * NOUT + ct * 16 + lr] = v[ct] - lse;
                }
            }
        }
    } else {
#pragma unroll
        for (int t = 0; t < 2; ++t) {
#pragma unroll
            for (int i = 0; i < 4; ++i) {
                int rr = rbase + t * 16 + lg * 4 + i;
                if (rr < M) {
                    float sc = 1.0f;
                    if constexpr (OMODE == 2) sc = rowscale[rr];
#pragma unroll
                    for (int ct = 0; ct < NT; ++ct) {
                        float v = acc[t][ct][i];
                        size_t o = (size_t)rr * NOUT + ct * 16 + lr;
                        if constexpr (OMODE == 0) {
                            outB[o] = f2bf(v + bv[ct]);
                        } else {  // OMODE == 2: fp8 e4m3 message
                            v *= sc;
                            int pk = __builtin_amdgcn_cvt_pk_fp8_f32(v, v, 0, false);
                            outQ[o] = (uint8_t)(pk & 0xff);
                        }
                    }
                }
            }
        }
    }
}

// ---------------- aggregation + bias + tanh + rezero (bf16 residual) ----------------
// one wave per node. B holds fp8 pre-scaled messages B'[s] = dinv[s]*(h@W)[s]
// (128B/row). csr holds BYTE offsets (src*128). Half-wave 0 = even edges,
// half-wave 1 = odd edges; 4B/lane covers 4 features; shfl_xor(32) combines.
// A[d] = bf16( beta*A[d] + alpha*tanh( dinv[d]*(sum + B'[d]) + b ) )

__global__ __launch_bounds__(256) void agg_kernel(
    const uint8_t* __restrict__ B, uint16_t* __restrict__ A,
    const float* __restrict__ dinv, const int* __restrict__ off,
    const int* __restrict__ csr, const float* __restrict__ bconv,
    const float* __restrict__ alpha, const float* __restrict__ beta,
    int n, int E)
{
    int gid = blockIdx.x * 256 + threadIdx.x;
    int d = gid >> 6;
    int lane = threadIdx.x & 63;
    if (d >= n) return;

    const int half = lane >> 5;
    const int c0 = (lane & 31) * 4;  // 4 features (bytes) per lane
    float a0 = 0.f, a1 = 0.f, a2 = 0.f, a3 = 0.f;
    const int s0 = off[d], s1 = off[d + 1];
    const int deg = s1 - s0;
    const int full = deg & ~63;

    for (int j0 = s0; j0 < s0 + full; j0 += 64) {
        int sv = csr[j0 + lane];  // byte offset of src row
        for (int it = 0; it < 64; it += 16) {  // 16 edges, 8 loads in flight
            uint32_t u[8];
#pragma unroll
            for (int q = 0; q < 8; ++q) {
                int o = __shfl(sv, it + 2 * q + half);
                u[q] = *(const uint32_t*)(B + o + c0);
            }
#pragma unroll
            for (int q = 0; q < 8; ++q) {
                f32x2 lo = __builtin_amdgcn_cvt_pk_f32_fp8((int)u[q], false);
                f32x2 hi = __builtin_amdgcn_cvt_pk_f32_fp8((int)u[q], true);
                a0 += lo[0]; a1 += lo[1]; a2 += hi[0]; a3 += hi[1];
            }
        }
    }
    int rem = deg - full;
    if (rem) {
        int idx = s0 + full + lane;
        int sv = csr[min(idx, E - 1)];
        for (int it = 0; it < rem; it += 16) {
            uint32_t u[8];
#pragma unroll
            for (int q = 0; q < 8; ++q) {
                int e = it + 2 * q + half;
                int o = __shfl(sv, e);
                u[q] = (e < rem) ? *(const uint32_t*)(B + o + c0) : 0u;
            }
#pragma unroll
            for (int q = 0; q < 8; ++q) {
                f32x2 lo = __builtin_amdgcn_cvt_pk_f32_fp8((int)u[q], false);
                f32x2 hi = __builtin_amdgcn_cvt_pk_f32_fp8((int)u[q], true);
                a0 += lo[0]; a1 += lo[1]; a2 += hi[0]; a3 += hi[1];
            }
        }
    }
    // combine the two half-wave partial sums
    a0 += __shfl_xor(a0, 32); a1 += __shfl_xor(a1, 32);
    a2 += __shfl_xor(a2, 32); a3 += __shfl_xor(a3, 32);
    // self loop (pre-scaled message of d itself)
    {
        uint32_t u = *(const uint32_t*)(B + ((size_t)d << 7) + c0);
        f32x2 lo = __builtin_amdgcn_cvt_pk_f32_fp8((int)u, false);
        f32x2 hi = __builtin_amdgcn_cvt_pk_f32_fp8((int)u, true);
        a0 += lo[0]; a1 += lo[1]; a2 += hi[0]; a3 += hi[1];
    }

    float dd = dinv[d];
    float al = alpha[0], be = beta[0];
    float4 bb = *(const float4*)(bconv + c0);
    uint2 ip = *(const uint2*)(A + (size_t)d * K + c0);
    float o0 = be * blo(ip.x) + al * tanhf(dd * a0 + bb.x);
    float o1 = be * bhi(ip.x) + al * tanhf(dd * a1 + bb.y);
    float o2 = be * blo(ip.y) + al * tanhf(dd * a2 + bb.z);
    float o3 = be * bhi(ip.y) + al * tanhf(dd * a3 + bb.w);
    if (half == 0) {
        uint2 pk;
        pk.x = ((uint32_t)f2bf(o1) << 16) | (uint32_t)f2bf(o0);
        pk.y = ((uint32_t)f2bf(o3) << 16) | (uint32_t)f2bf(o2);
        *(uint2*)(A + (size_t)d * K + c0) = pk;
    }
}

// ---------------------------------------------------------------------------

extern "C" void kernel_launch(void* const* d_in, const int* in_sizes, int n_in,
                              void* d_out, int out_size, void* d_ws, size_t ws_size,
                              hipStream_t stream)
{
    const float* x      = (const float*)d_in[0];
    const int*   ei     = (const int*)d_in[1];
    const float* W_in   = (const float*)d_in[2];
    const float* b_in   = (const float*)d_in[3];
    const float* W_conv = (const float*)d_in[4];
    const float* b_conv = (const float*)d_in[5];
    const float* alpha  = (const float*)d_in[6];
    const float* beta   = (const float*)d_in[7];
    const float* W_out  = (const float*)d_in[8];
    const float* b_out  = (const float*)d_in[9];
    float* out = (float*)d_out;

    const int N = in_sizes[0] / K;   // 100000
    const int E = in_sizes[1] / 2;   // 1600000
    const int L = in_sizes[6];       // 4

    const int* src = ei;
    const int* dst = ei + E;

    // workspace carve (16B-aligned by construction)
    char* p = (char*)d_ws;
    uint16_t* Abf = (uint16_t*)p;      p += (size_t)N * K * sizeof(uint16_t);  // 25.6 MB
    uint8_t* Bq8 = (uint8_t*)p;        p += (size_t)N * K * sizeof(uint8_t);   // 12.8 MB
    uint16_t* Wt_in = (uint16_t*)p;    p += (size_t)K * K * sizeof(uint16_t);
    uint16_t* Wt_conv = (uint16_t*)p;  p += (size_t)4 * K * K * sizeof(uint16_t);
    uint16_t* Wt_out = (uint16_t*)p;   p += (size_t)64 * K * sizeof(uint16_t);
    float* dinv = (float*)p;           p += (size_t)N * sizeof(float);
    int* off = (int*)p;                p += (size_t)(N + 1) * sizeof(int);
    int* csr = (int*)p;                p += (size_t)E * sizeof(int);
    int* ghist = (int*)p;              p += 1024 * sizeof(int);
    int* gbase = (int*)p;              p += 1025 * sizeof(int);
    int* gcur = (int*)p;               p += 1024 * sizeof(int);
    int* ebuf = (int*)p;               p += (size_t)E * sizeof(int);  // CSR-build staging

    // ---- CSR build (counting sort by dst) ----
    hipMemsetAsync(ghist, 0, 1024 * sizeof(int), stream);
    s1_hist<<<256, 256, 0, stream>>>(dst, ghist, E);
    s2_scan<<<1, 1024, 0, stream>>>(ghist, gbase, gcur, off, N, E);
    s3_scatter<<<(E + 4095) / 4096, 256, 0, stream>>>(src, dst, gcur, ebuf, E);
    s4_finalize<<<(N + 127) / 128, 256, 0, stream>>>(gbase, ebuf, csr, off, dinv, N, E);

    wconv_all<<<(90112 + 255) / 256, 256, 0, stream>>>(
        W_in, W_conv, W_out, Wt_in, Wt_conv, Wt_out);

    const int gblocks = (N + 127) / 128;
    // h0 = x @ W_in + b_in  -> Abf (bf16 residual)
    mfma_gemm<128, true, 0><<<gblocks, 256, 0, stream>>>(
        x, Wt_in, b_in, nullptr, Abf, nullptr, nullptr, N);
    for (int l = 0; l < L; ++l) {
        // Bq8 = fp8( dinv[row] * (Abf @ Wc) )   (pre-scaled messages)
        mfma_gemm<128, false, 2><<<gblocks, 256, 0, stream>>>(
            Abf, Wt_conv + (size_t)l * K * K, nullptr, nullptr, nullptr, Bq8, dinv, N);
        agg_kernel<<<(N * 64 + 255) / 256, 256, 0, stream>>>(
            Bq8, Abf, dinv, off, csr, b_conv + (size_t)l * K,
            alpha + l, beta + l, N, E);
    }
    // logits = Abf @ W_out + b_out, fused log_softmax, fp32 to d_out
    mfma_gemm<64, false, 1><<<gblocks, 256, 0, stream>>>(
        Abf, Wt_out, b_out, out, nullptr, nullptr, nullptr, N);
}